// Round 8
// baseline (266.754 us; speedup 1.0000x reference)
//
#include <hip/hip_runtime.h>
#include <hip/hip_bf16.h>
#include <math.h>

typedef unsigned short ushort_t;
typedef unsigned int uint_t;

// Problem constants
#define BB 32
#define PP 6
#define DD 96
#define EE 128
#define HH 8
#define II 64
#define KK 32
#define LSEQ 768            // N*D
#define ROWS (BB * LSEQ)    // 24576 token rows
#define OUTN 128
#define KOUT (LSEQ * EE)    // 98304

using bf16x8 = __attribute__((ext_vector_type(8))) short;
using bf16x4 = __attribute__((ext_vector_type(4))) short;
using f32x4  = __attribute__((ext_vector_type(4))) float;
using u32x4  = __attribute__((ext_vector_type(4))) uint_t;

__device__ __forceinline__ ushort_t f2b(float f) {
    __hip_bfloat16 h = __float2bfloat16(f);
    return *reinterpret_cast<ushort_t*>(&h);
}
// pack two fp32 -> (bf16(hi)<<16)|bf16(lo) by TRUNCATION: one v_perm_b32.
__device__ __forceinline__ uint_t permpack(float hi, float lo) {
    return __builtin_amdgcn_perm(__builtin_bit_cast(uint_t, hi),
                                 __builtin_bit_cast(uint_t, lo), 0x07060302u);
}
__device__ __forceinline__ float blo(uint_t u) {
    return __builtin_bit_cast(float, u << 16);
}
__device__ __forceinline__ float bhi(uint_t u) {
    return __builtin_bit_cast(float, u & 0xffff0000u);
}

// ---------------------------------------------------------------------------
// Merged cast + embed (unchanged from R7).
// ---------------------------------------------------------------------------
#define NCAST 320
__global__ __launch_bounds__(512) void cast_embed_kernel(
    const float* __restrict__ s0, int n0, const float* __restrict__ s1, int n1,
    const float* __restrict__ s2, int n2, const float* __restrict__ s3, int n3,
    ushort_t* __restrict__ d0, ushort_t* __restrict__ d1,
    ushort_t* __restrict__ d2, ushort_t* __restrict__ d3,
    const float* __restrict__ x, const float* __restrict__ prot,
    const float* __restrict__ emb_w, const float* __restrict__ emb_b,
    const float* __restrict__ proj_w, const float* __restrict__ proj_b,
    ushort_t* __restrict__ seq_bf)
{
    if (blockIdx.x < NCAST) {
        int i = blockIdx.x * 512 + threadIdx.x;
        if (i < n0) { d0[i] = f2b(s0[i]); return; }
        i -= n0;
        if (i < n1) { d1[i] = f2b(s1[i]); return; }
        i -= n1;
        if (i < n2) { d2[i] = f2b(s2[i]); return; }
        i -= n2;
        if (i < n3) { d3[i] = f2b(s3[i]); }
        return;
    }

    const int wave = threadIdx.x >> 6, lane = threadIdx.x & 63;
    const int r = (blockIdx.x - NCAST) * 8 + wave;
    const int d = r % DD;
    const int lpos = r % LSEQ;

    float xr[PP];
    float nx = 0.f;
    #pragma unroll
    for (int p = 0; p < PP; ++p) { xr[p] = x[r * PP + p]; nx += xr[p] * xr[p]; }
    const float xinv = 1.f / fmaxf(sqrtf(nx), 1e-12f);

    // proto sims, duplicated across the two 32-lane halves
    const int tk = lane & 31;
    const float* pr = prot + (d * KK + tk) * PP;
    float np2 = 0.f, dot = 0.f;
    #pragma unroll
    for (int p = 0; p < PP; ++p) {
        float pv = pr[p];
        np2 += pv * pv;
        dot += xr[p] * pv;
    }
    const float pinv = 1.f / fmaxf(sqrtf(np2), 1e-12f);
    float sim = dot * xinv * pinv;
    int k = tk;
    #pragma unroll
    for (int off = 16; off; off >>= 1) {
        float osim = __shfl_xor(sim, off);
        int   ok   = __shfl_xor(k, off);
        if (osim > sim || (osim == sim && ok < k)) { sim = osim; k = ok; }
    }
    // selected proto, normalized (recompute norm; all lanes agree on k)
    const float* sr = prot + (d * KK + k) * PP;
    float sp[PP], sn2 = 0.f;
    #pragma unroll
    for (int p = 0; p < PP; ++p) { sp[p] = sr[p]; sn2 += sp[p] * sp[p]; }
    const float spinv = 1.f / fmaxf(sqrtf(sn2), 1e-12f);

    #pragma unroll
    for (int c = 0; c < 2; ++c) {
        const int t = lane + c * 64;
        float acc = emb_b[t] + proj_b[t];
        #pragma unroll
        for (int p = 0; p < PP; ++p) {
            acc = fmaf(xr[p], emb_w[t * PP + p], acc);
            acc = fmaf(sp[p] * spinv, proj_w[t * PP + p], acc);
        }
        const float twoj = (float)((t >> 1) * 2);
        const float div = __expf(twoj * (-9.210340371976184f / 128.0f));
        const float ang = (float)lpos * div;
        const float pe = (t & 1) ? __cosf(ang) : __sinf(ang);
        seq_bf[(size_t)r * EE + t] = f2b(acc + pe);
    }
}

// ---------------------------------------------------------------------------
// QKV GEMM, attention-native outputs (unchanged from R7: LDS W staging).
// ---------------------------------------------------------------------------
__global__ __launch_bounds__(256) void gemm_qkv(
    const ushort_t* __restrict__ A, const ushort_t* __restrict__ W,
    const float* __restrict__ bias,
    ushort_t* __restrict__ q_bf, ushort_t* __restrict__ k2,
    ushort_t* __restrict__ v2)
{
    __shared__ ushort_t Ws[64 * 136];   // kp = 136 (K=128)
    const int t = threadIdx.x;
    const int wave = t >> 6, lane = t & 63;
    const int quad = lane >> 4, l16 = lane & 15;
    const int m0 = blockIdx.y * 128, n0 = blockIdx.x * 64;

    for (int c = t; c < 64 * 16; c += 256) {
        int row = c >> 4, col = c & 15;
        *(bf16x8*)&Ws[row * 136 + col * 8] =
            *(const bf16x8*)&W[(size_t)(n0 + row) * 128 + col * 8];
    }
    __syncthreads();

    f32x4 acc[2][4];
    #pragma unroll
    for (int s = 0; s < 2; ++s)
        #pragma unroll
        for (int nt = 0; nt < 4; ++nt)
            acc[s][nt] = (f32x4){0.f, 0.f, 0.f, 0.f};

    const ushort_t* a0p = A + (size_t)(m0 + wave * 32 + l16) * 128 + quad * 8;
    const ushort_t* a1p = a0p + (size_t)16 * 128;
    const ushort_t* wp  = &Ws[l16 * 136 + quad * 8];

    #pragma unroll
    for (int k0 = 0; k0 < 128; k0 += 32) {
        bf16x8 a0 = *(const bf16x8*)(a0p + k0);
        bf16x8 a1 = *(const bf16x8*)(a1p + k0);
        #pragma unroll
        for (int nt = 0; nt < 4; ++nt) {
            bf16x8 wf = *(const bf16x8*)(wp + nt * 16 * 136 + k0);
            acc[0][nt] = __builtin_amdgcn_mfma_f32_16x16x32_bf16(wf, a0, acc[0][nt], 0, 0, 0);
            acc[1][nt] = __builtin_amdgcn_mfma_f32_16x16x32_bf16(wf, a1, acc[1][nt], 0, 0, 0);
        }
    }

    const int b = blockIdx.y / 6;            // 6 m-blocks per batch (768/128)
    #pragma unroll
    for (int s = 0; s < 2; ++s) {
        const int m = m0 + wave * 32 + s * 16 + l16;
        const int l = m - b * LSEQ;          // position within sequence
        const int c32 = l >> 5, u = l & 31;
        #pragma unroll
        for (int nt = 0; nt < 4; ++nt) {
            const int nb = n0 + nt * 16 + quad * 4;
            float4 b4 = *(const float4*)&bias[nb];
            float v[4];
            #pragma unroll
            for (int r = 0; r < 4; ++r)
                v[r] = acc[s][nt][r] + ((const float*)&b4)[r];

            if (n0 < 128) {
                // Q: pre-scale by 1/sqrt(16) * log2(e)
                #pragma unroll
                for (int r = 0; r < 4; ++r) v[r] *= 0.36067376022224085f;
                uint2 w2;
                w2.x = permpack(v[1], v[0]);
                w2.y = permpack(v[3], v[2]);
                *(uint2*)&q_bf[(size_t)m * EE + nb] = w2;
            } else if (n0 < 256) {
                const int h = ((n0 - 128) >> 4) + nt;
                const int half = (u >> 2) & 1;
                const int mm = ((u >> 3) << 2) | (u & 3);
                uint2 w2;
                w2.x = permpack(v[1], v[0]);
                w2.y = permpack(v[3], v[2]);
                *(uint2*)&k2[((((((size_t)(b * HH + h)) * 24 + c32) * 2 + half) * 4 + quad) * 16 + mm) * 4] = w2;
            } else {
                const int h = ((n0 - 256) >> 4) + nt;
                const size_t vb = (((size_t)(b * HH + h)) * 24 + c32) * 512;
                #pragma unroll
                for (int r = 0; r < 4; ++r)
                    v2[vb + (quad * 4 + r) * 32 + u] = f2b(v[r]);
            }
        }
    }
}

// ---------------------------------------------------------------------------
// MFMA flash attention v9 (unchanged).
// ---------------------------------------------------------------------------
__device__ __forceinline__ void attn_step32(
    bf16x4 kf0, bf16x4 kf1, bf16x8 vf, const bf16x4 (&qf)[2],
    f32x4 (&oacc)[2], f32x4 (&lacc)[2], bf16x8 ones8)
{
    const f32x4 zero4 = (f32x4){0.f, 0.f, 0.f, 0.f};
    #pragma unroll
    for (int s = 0; s < 2; ++s) {
        f32x4 sv0 = __builtin_amdgcn_mfma_f32_16x16x16bf16_1k(kf0, qf[s], zero4, 0, 0, 0);
        f32x4 sv1 = __builtin_amdgcn_mfma_f32_16x16x16bf16_1k(kf1, qf[s], zero4, 0, 0, 0);
        float e0 = __builtin_amdgcn_exp2f(sv0[0]);
        float e1 = __builtin_amdgcn_exp2f(sv0[1]);
        float e2 = __builtin_amdgcn_exp2f(sv0[2]);
        float e3 = __builtin_amdgcn_exp2f(sv0[3]);
        float e4 = __builtin_amdgcn_exp2f(sv1[0]);
        float e5 = __builtin_amdgcn_exp2f(sv1[1]);
        float e6 = __builtin_amdgcn_exp2f(sv1[2]);
        float e7 = __builtin_amdgcn_exp2f(sv1[3]);
        u32x4 pu;
        pu[0] = permpack(e1, e0);
        pu[1] = permpack(e3, e2);
        pu[2] = permpack(e5, e4);
        pu[3] = permpack(e7, e6);
        bf16x8 pf = __builtin_bit_cast(bf16x8, pu);
        oacc[s] = __builtin_amdgcn_mfma_f32_16x16x32_bf16(vf, pf, oacc[s], 0, 0, 0);
        lacc[s] = __builtin_amdgcn_mfma_f32_16x16x32_bf16(ones8, pf, lacc[s], 0, 0, 0);
    }
}

__global__ __launch_bounds__(256) void attention_mfma(
    const ushort_t* __restrict__ q_bf, const ushort_t* __restrict__ k2,
    const ushort_t* __restrict__ v2, ushort_t* __restrict__ ctx)
{
    const int bh = blockIdx.x;
    const int b = bh & 31, h = bh >> 5;     // XCD swizzle: id%8 == b%8
    const int qb = blockIdx.y;              // 0..5, 128 q each
    const int t = threadIdx.x;
    const int wave = t >> 6, lane = t & 63;
    const int quad = lane >> 4, l16 = lane & 15;
    const int hoff = h * 16;

    // Q fragments (one-time gather)
    bf16x4 qf[2];
    #pragma unroll
    for (int s = 0; s < 2; ++s) {
        int row = b * LSEQ + qb * 128 + wave * 32 + s * 16 + l16;
        qf[s] = *(const bf16x4*)&q_bf[(size_t)row * EE + hoff + quad * 4];
    }

    const int bhn = b * HH + h;
    const ushort_t* kp = k2 + (size_t)bhn * 12288 + quad * 64 + l16 * 4;
    const ushort_t* vp = v2 + (size_t)bhn * 12288 + l16 * 32 + quad * 8;

    f32x4 oacc[2], lacc[2];
    oacc[0] = (f32x4){0.f, 0.f, 0.f, 0.f};
    oacc[1] = (f32x4){0.f, 0.f, 0.f, 0.f};
    lacc[0] = (f32x4){0.f, 0.f, 0.f, 0.f};
    lacc[1] = (f32x4){0.f, 0.f, 0.f, 0.f};
    bf16x8 ones8;
    #pragma unroll
    for (int j = 0; j < 8; ++j) ones8[j] = (short)0x3F80;   // bf16 1.0

    bf16x4 k0a = *(const bf16x4*)(kp);
    bf16x4 k1a = *(const bf16x4*)(kp + 256);
    bf16x8 va  = *(const bf16x8*)(vp);
    bf16x4 k0b = *(const bf16x4*)(kp + 512);
    bf16x4 k1b = *(const bf16x4*)(kp + 768);
    bf16x8 vb  = *(const bf16x8*)(vp + 512);
    bf16x4 k0c = *(const bf16x4*)(kp + 1024);
    bf16x4 k1c = *(const bf16x4*)(kp + 1280);
    bf16x8 vc  = *(const bf16x8*)(vp + 1024);

    for (int c0 = 0; c0 < 24; c0 += 3) {
        attn_step32(k0a, k1a, va, qf, oacc, lacc, ones8);
        { int n = c0 + 3; if (n >= 24) n -= 24;
          k0a = *(const bf16x4*)(kp + n * 512);
          k1a = *(const bf16x4*)(kp + n * 512 + 256);
          va  = *(const bf16x8*)(vp + n * 512); }
        attn_step32(k0b, k1b, vb, qf, oacc, lacc, ones8);
        { int n = c0 + 4; if (n >= 24) n -= 24;
          k0b = *(const bf16x4*)(kp + n * 512);
          k1b = *(const bf16x4*)(kp + n * 512 + 256);
          vb  = *(const bf16x8*)(vp + n * 512); }
        attn_step32(k0c, k1c, vc, qf, oacc, lacc, ones8);
        { int n = c0 + 5; if (n >= 24) n -= 24;
          k0c = *(const bf16x4*)(kp + n * 512);
          k1c = *(const bf16x4*)(kp + n * 512 + 256);
          vc  = *(const bf16x8*)(vp + n * 512); }
    }

    #pragma unroll
    for (int s = 0; s < 2; ++s) {
        const float inv = 1.f / lacc[s][0];     // row-replicated full sum
        const int q = qb * 128 + wave * 32 + s * 16 + l16;
        uint2 w2;
        w2.x = permpack(oacc[s][1] * inv, oacc[s][0] * inv);
        w2.y = permpack(oacc[s][3] * inv, oacc[s][2] * inv);
        *(uint2*)&ctx[((size_t)(b * LSEQ + q)) * EE + hoff + quad * 4] = w2;
    }
}

// ---------------------------------------------------------------------------
// Fused attn-out GEMM + LN1 + FFN + LN2, v3: 32-row blocks x 128 threads ->
// 768 blocks = exactly 3/CU (was 384 = 1.5/CU, ~75% utilization). Per-wave
// work identical to v2 (each wave owns 16 rows end-to-end); LDS 48 KB.
// ---------------------------------------------------------------------------
#define W1OFF 0
#define W2OFF 8704
#define YOFF  17920
#define HOFF  22272
__global__ __launch_bounds__(128) void gemm_ln_ffn(
    const ushort_t* __restrict__ ctx_bf, const ushort_t* __restrict__ Wout,
    const float* __restrict__ bout,
    const float* __restrict__ g1, const float* __restrict__ be1,
    const ushort_t* __restrict__ W1, const float* __restrict__ b1,
    const ushort_t* __restrict__ W2, const float* __restrict__ b2,
    const float* __restrict__ g2, const float* __restrict__ be2,
    ushort_t* __restrict__ seq_bf)
{
    __shared__ ushort_t S[24576];           // 49152 B
    const int t = threadIdx.x;
    const int wave = t >> 6, lane = t & 63;
    const int quad = lane >> 4, l16 = lane & 15;
    const int m0 = blockIdx.x * 32;
    const int lrow = wave * 16 + l16;       // 0..31
    const int m = m0 + lrow;

    // ---- stage Wout (128 x 136) into S[0..17408 elems) ----
    for (int c = t; c < 128 * 16; c += 128) {
        int row = c >> 4, col = c & 15;
        *(bf16x8*)&S[row * 136 + col * 8] =
            *(const bf16x8*)&Wout[(size_t)row * 128 + col * 8];
    }
    __syncthreads();

    // ---- GEMM A: attn_out = ctx @ Wout^T ----
    f32x4 acc[8];
    #pragma unroll
    for (int nt = 0; nt < 8; ++nt) acc[nt] = (f32x4){0.f, 0.f, 0.f, 0.f};
    {
        const ushort_t* ap = ctx_bf + (size_t)m * EE + quad * 8;
        const ushort_t* wp = &S[l16 * 136 + quad * 8];
        #pragma unroll
        for (int k0 = 0; k0 < 128; k0 += 32) {
            bf16x8 a = *(const bf16x8*)(ap + k0);
            #pragma unroll
            for (int nt = 0; nt < 8; ++nt) {
                bf16x8 wf = *(const bf16x8*)(wp + nt * 16 * 136 + k0);
                acc[nt] = __builtin_amdgcn_mfma_f32_16x16x32_bf16(wf, a, acc[nt], 0, 0, 0);
            }
        }
    }
    __syncthreads();   // all waves done reading Wout; its LDS may be reused

    // ---- stage W1 (64x136) and W2 (128x72) over the Wout region ----
    for (int c = t; c < 64 * 16; c += 128) {
        int row = c >> 4, col = c & 15;
        *(bf16x8*)&S[W1OFF + row * 136 + col * 8] =
            *(const bf16x8*)&W1[(size_t)row * 128 + col * 8];
    }
    for (int c = t; c < 128 * 8; c += 128) {
        int row = c >> 3, col = c & 7;
        *(bf16x8*)&S[W2OFF + row * 72 + col * 8] =
            *(const bf16x8*)&W2[(size_t)row * 64 + col * 8];
    }

    // ---- epilogue A: + bias + residual(bf16), LN1 -> y (regs + LDS bf16) ----
    float y[8][4];
    float s = 0.f;
    #pragma unroll
    for (int nt = 0; nt < 8; ++nt) {
        const int nb = nt * 16 + quad * 4;
        float4 b4 = *(const float4*)&bout[nb];
        uint2 rr = *(const uint2*)&seq_bf[(size_t)m * EE + nb];
        float rv[4] = {blo(rr.x), bhi(rr.x), blo(rr.y), bhi(rr.y)};
        #pragma unroll
        for (int r = 0; r < 4; ++r) {
            y[nt][r] = acc[nt][r] + ((const float*)&b4)[r] + rv[r];
            s += y[nt][r];
        }
    }
    s += __shfl_xor(s, 16);
    s += __shfl_xor(s, 32);
    float mean = s * (1.f / 128.f);
    float s2 = 0.f;
    #pragma unroll
    for (int nt = 0; nt < 8; ++nt)
        #pragma unroll
        for (int r = 0; r < 4; ++r) {
            float d = y[nt][r] - mean;
            s2 += d * d;
        }
    s2 += __shfl_xor(s2, 16);
    s2 += __shfl_xor(s2, 32);
    float rstd = 1.f / sqrtf(s2 * (1.f / 128.f) + 1e-5f);

    #pragma unroll
    for (int nt = 0; nt < 8; ++nt) {
        const int nb = nt * 16 + quad * 4;
        float4 g4 = *(const float4*)&g1[nb];
        float4 be4 = *(const float4*)&be1[nb];
        #pragma unroll
        for (int r = 0; r < 4; ++r)
            y[nt][r] = (y[nt][r] - mean) * rstd * ((const float*)&g4)[r] + ((const float*)&be4)[r];
        uint2 w2;
        w2.x = permpack(y[nt][1], y[nt][0]);
        w2.y = permpack(y[nt][3], y[nt][2]);
        *(uint2*)&S[YOFF + lrow * 136 + nb] = w2;
    }
    __syncthreads();   // Ybf + W1 + W2 visible

    // ---- GEMM 1: h = elu(y @ W1^T + b1) ----
    f32x4 acc1[4];
    #pragma unroll
    for (int nt = 0; nt < 4; ++nt) acc1[nt] = (f32x4){0.f, 0.f, 0.f, 0.f};
    {
        const ushort_t* ap1 = &S[YOFF + lrow * 136 + quad * 8];
        const ushort_t* w1p = &S[W1OFF + l16 * 136 + quad * 8];
        #pragma unroll
        for (int k0 = 0; k0 < 128; k0 += 32) {
            bf16x8 a = *(const bf16x8*)(ap1 + k0);
            #pragma unroll
            for (int nt = 0; nt < 4; ++nt) {
                bf16x8 wf = *(const bf16x8*)(w1p + nt * 16 * 136 + k0);
                acc1[nt] = __builtin_amdgcn_mfma_f32_16x16x32_bf16(wf, a, acc1[nt], 0, 0, 0);
            }
        }
    }
    #pragma unroll
    for (int nt = 0; nt < 4; ++nt) {
        const int ib = nt * 16 + quad * 4;
        float4 b4 = *(const float4*)&b1[ib];
        float hv[4];
        #pragma unroll
        for (int r = 0; r < 4; ++r) {
            float u = acc1[nt][r] + ((const float*)&b4)[r];
            hv[r] = u > 0.f ? u : expm1f(u);
        }
        uint2 w2;
        w2.x = permpack(hv[1], hv[0]);
        w2.y = permpack(hv[3], hv[2]);
        *(uint2*)&S[HOFF + lrow * 72 + ib] = w2;   // wave-private rows
    }

    // ---- GEMM 2: ffn = h @ W2^T + b2 (reads only this lane's row) ----
    f32x4 acc2[8];
    #pragma unroll
    for (int nt = 0; nt < 8; ++nt) acc2[nt] = (f32x4){0.f, 0.f, 0.f, 0.f};
    {
        const ushort_t* hp  = &S[HOFF + lrow * 72 + quad * 8];
        const ushort_t* w2p = &S[W2OFF + l16 * 72 + quad * 8];
        #pragma unroll
        for (int k0 = 0; k0 < 64; k0 += 32) {
            bf16x8 hf = *(const bf16x8*)(hp + k0);
            #pragma unroll
            for (int nt = 0; nt < 8; ++nt) {
                bf16x8 wf = *(const bf16x8*)(w2p + nt * 16 * 72 + k0);
                acc2[nt] = __builtin_amdgcn_mfma_f32_16x16x32_bf16(wf, hf, acc2[nt], 0, 0, 0);
            }
        }
    }

    // ---- epilogue B: + bias + residual(y regs), LN2, store bf16 ----
    float v[8][4];
    s = 0.f;
    #pragma unroll
    for (int nt = 0; nt < 8; ++nt) {
        const int nb = nt * 16 + quad * 4;
        float4 b4 = *(const float4*)&b2[nb];
        #pragma unroll
        for (int r = 0; r < 4; ++r) {
            v[nt][r] = acc2[nt][r] + ((const float*)&b4)[r] + y[nt][r];
            s += v[nt][r];
        }
    }
    s += __shfl_xor(s, 16);
    s += __shfl_xor(s, 32);
    mean = s * (1.f / 128.f);
    s2 = 0.f;
    #pragma unroll
    for (int nt = 0; nt < 8; ++nt)
        #pragma unroll
        for (int r = 0; r < 4; ++r) {
            float d = v[nt][r] - mean;
            s2 += d * d;
        }
    s2 += __shfl_xor(s2, 16);
    s2 += __shfl_xor(s2, 32);
    rstd = 1.f / sqrtf(s2 * (1.f / 128.f) + 1e-5f);

    #pragma unroll
    for (int nt = 0; nt < 8; ++nt) {
        const int nb = nt * 16 + quad * 4;
        float4 g4 = *(const float4*)&g2[nb];
        float4 be4 = *(const float4*)&be2[nb];
        float o[4];
        #pragma unroll
        for (int r = 0; r < 4; ++r)
            o[r] = (v[nt][r] - mean) * rstd * ((const float*)&g4)[r] + ((const float*)&be4)[r];
        uint2 w2;
        w2.x = permpack(o[1], o[0]);
        w2.y = permpack(o[3], o[2]);
        *(uint2*)&seq_bf[(size_t)m * EE + nb] = w2;
    }
}

// ---------------------------------------------------------------------------
// Final projection, split-K MFMA. PKC 384->192: 512 blocks = 2/CU = 8
// waves/CU, doubling outstanding loads on the cold 50 MB out_w stream.
// ---------------------------------------------------------------------------
#define PKC 192
#define PNBLK (KOUT / PKC)   // 512
__global__ __launch_bounds__(256) void out_gemm3(
    const ushort_t* __restrict__ seqbf, const float* __restrict__ out_w,
    float* __restrict__ part)
{
    const int t = threadIdx.x;
    const int wave = t >> 6, lane = t & 63;
    const int quad = lane >> 4, l16 = lane & 15;
    const size_t k0 = (size_t)blockIdx.x * PKC;
    const int n0 = wave * 32;

    f32x4 acc[2][2];
    #pragma unroll
    for (int mt = 0; mt < 2; ++mt)
        #pragma unroll
        for (int nt = 0; nt < 2; ++nt)
            acc[mt][nt] = (f32x4){0.f, 0.f, 0.f, 0.f};

    const ushort_t* a0p = seqbf + (size_t)l16 * KOUT + k0 + quad * 8;
    const ushort_t* a1p = a0p + (size_t)16 * KOUT;
    const float* w0p = out_w + (size_t)(n0 + l16) * KOUT + k0 + quad * 8;
    const float* w1p = w0p + (size_t)16 * KOUT;

    for (int ks = 0; ks < PKC; ks += 32) {
        bf16x8 a0 = *(const bf16x8*)(a0p + ks);
        bf16x8 a1 = *(const bf16x8*)(a1p + ks);
        float4 wa0 = *(const float4*)(w0p + ks);
        float4 wa1 = *(const float4*)(w0p + ks + 4);
        float4 wb0 = *(const float4*)(w1p + ks);
        float4 wb1 = *(const float4*)(w1p + ks + 4);
        u32x4 b0, b1;
        b0[0] = permpack(wa0.y, wa0.x); b0[1] = permpack(wa0.w, wa0.z);
        b0[2] = permpack(wa1.y, wa1.x); b0[3] = permpack(wa1.w, wa1.z);
        b1[0] = permpack(wb0.y, wb0.x); b1[1] = permpack(wb0.w, wb0.z);
        b1[2] = permpack(wb1.y, wb1.x); b1[3] = permpack(wb1.w, wb1.z);
        bf16x8 bf0 = __builtin_bit_cast(bf16x8, b0);
        bf16x8 bf1 = __builtin_bit_cast(bf16x8, b1);
        acc[0][0] = __builtin_amdgcn_mfma_f32_16x16x32_bf16(a0, bf0, acc[0][0], 0, 0, 0);
        acc[1][0] = __builtin_amdgcn_mfma_f32_16x16x32_bf16(a1, bf0, acc[1][0], 0, 0, 0);
        acc[0][1] = __builtin_amdgcn_mfma_f32_16x16x32_bf16(a0, bf1, acc[0][1], 0, 0, 0);
        acc[1][1] = __builtin_amdgcn_mfma_f32_16x16x32_bf16(a1, bf1, acc[1][1], 0, 0, 0);
    }

    float* pb = part + (size_t)blockIdx.x * (32 * 128);
    #pragma unroll
    for (int mt = 0; mt < 2; ++mt)
        #pragma unroll
        for (int nt = 0; nt < 2; ++nt)
            #pragma unroll
            for (int r = 0; r < 4; ++r)
                pb[(mt * 16 + quad * 4 + r) * 128 + n0 + nt * 16 + l16] = acc[mt][nt][r];
}

// ---------------------------------------------------------------------------
// Single fused reduction over 512 split-K partials: 128 blocks, 8 sub-sums
// of 64 partials each, LDS combine.
// ---------------------------------------------------------------------------
__global__ __launch_bounds__(256) void out_reduce(
    const float* __restrict__ part, const float* __restrict__ out_b,
    float* __restrict__ out)
{
    __shared__ float red[8][32];
    const int g = threadIdx.x & 31, sub = threadIdx.x >> 5;
    const int i = blockIdx.x * 32 + g;
    const float* p = part + (size_t)sub * 64 * 4096 + i;
    float s0 = 0.f, s1 = 0.f, s2 = 0.f, s3 = 0.f;
    for (int blk = 0; blk < 64; blk += 4) {
        s0 += p[(size_t)blk * 4096];
        s1 += p[(size_t)(blk + 1) * 4096];
        s2 += p[(size_t)(blk + 2) * 4096];
        s3 += p[(size_t)(blk + 3) * 4096];
    }
    red[sub][g] = (s0 + s1) + (s2 + s3);
    __syncthreads();
    if (sub == 0) {
        float s = 0.f;
        #pragma unroll
        for (int j = 0; j < 8; ++j) s += red[j][g];
        out[i] = out_b[i & (OUTN - 1)] + s;
    }
}

// ---------------------------------------------------------------------------
extern "C" void kernel_launch(void* const* d_in, const int* in_sizes, int n_in,
                              void* d_out, int out_size, void* d_ws, size_t ws_size,
                              hipStream_t stream)
{
    const float* x          = (const float*)d_in[0];
    const float* prototypes = (const float*)d_in[1];
    const float* emb_w      = (const float*)d_in[2];
    const float* emb_b      = (const float*)d_in[3];
    const float* proj_w     = (const float*)d_in[4];
    const float* proj_b     = (const float*)d_in[5];
    const float* in_proj_w  = (const float*)d_in[6];
    const float* in_proj_b  = (const float*)d_in[7];
    const float* out_proj_w = (const float*)d_in[8];
    const float* out_proj_b = (const float*)d_in[9];
    const float* ln1_s      = (const float*)d_in[10];
    const float* ln1_b      = (const float*)d_in[11];
    const float* ffn_w1     = (const float*)d_in[12];
    const float* ffn_b1     = (const float*)d_in[13];
    const float* ffn_w2     = (const float*)d_in[14];
    const float* ffn_b2     = (const float*)d_in[15];
    const float* ln2_s      = (const float*)d_in[16];
    const float* ln2_b      = (const float*)d_in[17];
    const float* out_w      = (const float*)d_in[18];
    const float* out_b      = (const float*)d_in[19];
    float* out = (float*)d_out;
    char* base = (char*)d_ws;

    float*    part   = (float*)base;                        // 8 MB
    ushort_t* seq_bf = (ushort_t*)(base + 25165824);        //  6,291,456
    ushort_t* q_bf   = (ushort_t*)(base + 31457280);        //  6,291,456
    ushort_t* k2     = (ushort_t*)(base + 37748736);        //  6,291,456
    ushort_t* v2     = (ushort_t*)(base + 44040192);        //  6,291,456
    ushort_t* ctx_bf = (ushort_t*)(base + 50331648);        //  6,291,456
    ushort_t* w_bf   = (ushort_t*)(base + 56623104);        //    327,680
    (void)ws_size;

    ushort_t* w_in  = w_bf;            // [2][384][128]
    ushort_t* w_out = w_bf + 98304;    // [2][128][128]
    ushort_t* w_f1  = w_bf + 131072;   // [2][64][128]
    ushort_t* w_f2  = w_bf + 147456;   // [2][128][64]

    // merged cast (320 blocks) + embed (3072 blocks, 8 rows each)
    cast_embed_kernel<<<NCAST + ROWS / 8, 512, 0, stream>>>(
        in_proj_w, 98304, out_proj_w, 32768, ffn_w1, 16384, ffn_w2, 16384,
        w_in, w_out, w_f1, w_f2,
        x, prototypes, emb_w, emb_b, proj_w, proj_b, seq_bf);

    for (int l = 0; l < 2; ++l) {
        gemm_qkv<<<dim3(6, 192), 256, 0, stream>>>(
            seq_bf, w_in + (size_t)l * 49152, in_proj_b + l * 384,
            q_bf, k2, v2);
        attention_mfma<<<dim3(BB * HH, 6), 256, 0, stream>>>(q_bf, k2, v2, ctx_bf);
        // seq = LN2(LN1(seq + ctx@Wout^T + b) + FFN(...)) fully fused
        gemm_ln_ffn<<<ROWS / 32, 128, 0, stream>>>(
            ctx_bf, w_out + (size_t)l * 16384, out_proj_b + l * 128,
            ln1_s + l * EE, ln1_b + l * EE,
            w_f1 + (size_t)l * 8192, ffn_b1 + l * II,
            w_f2 + (size_t)l * 8192, ffn_b2 + l * EE,
            ln2_s + l * EE, ln2_b + l * EE,
            seq_bf);
    }

    out_gemm3<<<PNBLK, 256, 0, stream>>>(seq_bf, out_w, part);
    out_reduce<<<OUTN * BB / 32, 256, 0, stream>>>(part, out_b, out);
}

// Round 9
// 256.628 us; speedup vs baseline: 1.0395x; 1.0395x over previous
//
#include <hip/hip_runtime.h>
#include <hip/hip_bf16.h>
#include <math.h>

typedef unsigned short ushort_t;
typedef unsigned int uint_t;

// Problem constants
#define BB 32
#define PP 6
#define DD 96
#define EE 128
#define HH 8
#define II 64
#define KK 32
#define LSEQ 768            // N*D
#define ROWS (BB * LSEQ)    // 24576 token rows
#define OUTN 128
#define KOUT (LSEQ * EE)    // 98304

using bf16x8 = __attribute__((ext_vector_type(8))) short;
using bf16x4 = __attribute__((ext_vector_type(4))) short;
using f32x4  = __attribute__((ext_vector_type(4))) float;
using u32x4  = __attribute__((ext_vector_type(4))) uint_t;

__device__ __forceinline__ ushort_t f2b(float f) {
    __hip_bfloat16 h = __float2bfloat16(f);
    return *reinterpret_cast<ushort_t*>(&h);
}
// pack two fp32 -> (bf16(hi)<<16)|bf16(lo) by TRUNCATION: one v_perm_b32.
__device__ __forceinline__ uint_t permpack(float hi, float lo) {
    return __builtin_amdgcn_perm(__builtin_bit_cast(uint_t, hi),
                                 __builtin_bit_cast(uint_t, lo), 0x07060302u);
}
__device__ __forceinline__ float blo(uint_t u) {
    return __builtin_bit_cast(float, u << 16);
}
__device__ __forceinline__ float bhi(uint_t u) {
    return __builtin_bit_cast(float, u & 0xffff0000u);
}

// ---------------------------------------------------------------------------
// Merged cast + embed (unchanged from R7).
// ---------------------------------------------------------------------------
#define NCAST 320
__global__ __launch_bounds__(512) void cast_embed_kernel(
    const float* __restrict__ s0, int n0, const float* __restrict__ s1, int n1,
    const float* __restrict__ s2, int n2, const float* __restrict__ s3, int n3,
    ushort_t* __restrict__ d0, ushort_t* __restrict__ d1,
    ushort_t* __restrict__ d2, ushort_t* __restrict__ d3,
    const float* __restrict__ x, const float* __restrict__ prot,
    const float* __restrict__ emb_w, const float* __restrict__ emb_b,
    const float* __restrict__ proj_w, const float* __restrict__ proj_b,
    ushort_t* __restrict__ seq_bf)
{
    if (blockIdx.x < NCAST) {
        int i = blockIdx.x * 512 + threadIdx.x;
        if (i < n0) { d0[i] = f2b(s0[i]); return; }
        i -= n0;
        if (i < n1) { d1[i] = f2b(s1[i]); return; }
        i -= n1;
        if (i < n2) { d2[i] = f2b(s2[i]); return; }
        i -= n2;
        if (i < n3) { d3[i] = f2b(s3[i]); }
        return;
    }

    const int wave = threadIdx.x >> 6, lane = threadIdx.x & 63;
    const int r = (blockIdx.x - NCAST) * 8 + wave;
    const int d = r % DD;
    const int lpos = r % LSEQ;

    float xr[PP];
    float nx = 0.f;
    #pragma unroll
    for (int p = 0; p < PP; ++p) { xr[p] = x[r * PP + p]; nx += xr[p] * xr[p]; }
    const float xinv = 1.f / fmaxf(sqrtf(nx), 1e-12f);

    // proto sims, duplicated across the two 32-lane halves
    const int tk = lane & 31;
    const float* pr = prot + (d * KK + tk) * PP;
    float np2 = 0.f, dot = 0.f;
    #pragma unroll
    for (int p = 0; p < PP; ++p) {
        float pv = pr[p];
        np2 += pv * pv;
        dot += xr[p] * pv;
    }
    const float pinv = 1.f / fmaxf(sqrtf(np2), 1e-12f);
    float sim = dot * xinv * pinv;
    int k = tk;
    #pragma unroll
    for (int off = 16; off; off >>= 1) {
        float osim = __shfl_xor(sim, off);
        int   ok   = __shfl_xor(k, off);
        if (osim > sim || (osim == sim && ok < k)) { sim = osim; k = ok; }
    }
    // selected proto, normalized (recompute norm; all lanes agree on k)
    const float* sr = prot + (d * KK + k) * PP;
    float sp[PP], sn2 = 0.f;
    #pragma unroll
    for (int p = 0; p < PP; ++p) { sp[p] = sr[p]; sn2 += sp[p] * sp[p]; }
    const float spinv = 1.f / fmaxf(sqrtf(sn2), 1e-12f);

    #pragma unroll
    for (int c = 0; c < 2; ++c) {
        const int t = lane + c * 64;
        float acc = emb_b[t] + proj_b[t];
        #pragma unroll
        for (int p = 0; p < PP; ++p) {
            acc = fmaf(xr[p], emb_w[t * PP + p], acc);
            acc = fmaf(sp[p] * spinv, proj_w[t * PP + p], acc);
        }
        const float twoj = (float)((t >> 1) * 2);
        const float div = __expf(twoj * (-9.210340371976184f / 128.0f));
        const float ang = (float)lpos * div;
        const float pe = (t & 1) ? __cosf(ang) : __sinf(ang);
        seq_bf[(size_t)r * EE + t] = f2b(acc + pe);
    }
}

// ---------------------------------------------------------------------------
// QKV GEMM, attention-native outputs (unchanged from R7: LDS W staging).
// ---------------------------------------------------------------------------
__global__ __launch_bounds__(256) void gemm_qkv(
    const ushort_t* __restrict__ A, const ushort_t* __restrict__ W,
    const float* __restrict__ bias,
    ushort_t* __restrict__ q_bf, ushort_t* __restrict__ k2,
    ushort_t* __restrict__ v2)
{
    __shared__ ushort_t Ws[64 * 136];   // kp = 136 (K=128)
    const int t = threadIdx.x;
    const int wave = t >> 6, lane = t & 63;
    const int quad = lane >> 4, l16 = lane & 15;
    const int m0 = blockIdx.y * 128, n0 = blockIdx.x * 64;

    for (int c = t; c < 64 * 16; c += 256) {
        int row = c >> 4, col = c & 15;
        *(bf16x8*)&Ws[row * 136 + col * 8] =
            *(const bf16x8*)&W[(size_t)(n0 + row) * 128 + col * 8];
    }
    __syncthreads();

    f32x4 acc[2][4];
    #pragma unroll
    for (int s = 0; s < 2; ++s)
        #pragma unroll
        for (int nt = 0; nt < 4; ++nt)
            acc[s][nt] = (f32x4){0.f, 0.f, 0.f, 0.f};

    const ushort_t* a0p = A + (size_t)(m0 + wave * 32 + l16) * 128 + quad * 8;
    const ushort_t* a1p = a0p + (size_t)16 * 128;
    const ushort_t* wp  = &Ws[l16 * 136 + quad * 8];

    #pragma unroll
    for (int k0 = 0; k0 < 128; k0 += 32) {
        bf16x8 a0 = *(const bf16x8*)(a0p + k0);
        bf16x8 a1 = *(const bf16x8*)(a1p + k0);
        #pragma unroll
        for (int nt = 0; nt < 4; ++nt) {
            bf16x8 wf = *(const bf16x8*)(wp + nt * 16 * 136 + k0);
            acc[0][nt] = __builtin_amdgcn_mfma_f32_16x16x32_bf16(wf, a0, acc[0][nt], 0, 0, 0);
            acc[1][nt] = __builtin_amdgcn_mfma_f32_16x16x32_bf16(wf, a1, acc[1][nt], 0, 0, 0);
        }
    }

    const int b = blockIdx.y / 6;            // 6 m-blocks per batch (768/128)
    #pragma unroll
    for (int s = 0; s < 2; ++s) {
        const int m = m0 + wave * 32 + s * 16 + l16;
        const int l = m - b * LSEQ;          // position within sequence
        const int c32 = l >> 5, u = l & 31;
        #pragma unroll
        for (int nt = 0; nt < 4; ++nt) {
            const int nb = n0 + nt * 16 + quad * 4;
            float4 b4 = *(const float4*)&bias[nb];
            float v[4];
            #pragma unroll
            for (int r = 0; r < 4; ++r)
                v[r] = acc[s][nt][r] + ((const float*)&b4)[r];

            if (n0 < 128) {
                // Q: pre-scale by 1/sqrt(16) * log2(e)
                #pragma unroll
                for (int r = 0; r < 4; ++r) v[r] *= 0.36067376022224085f;
                uint2 w2;
                w2.x = permpack(v[1], v[0]);
                w2.y = permpack(v[3], v[2]);
                *(uint2*)&q_bf[(size_t)m * EE + nb] = w2;
            } else if (n0 < 256) {
                const int h = ((n0 - 128) >> 4) + nt;
                const int half = (u >> 2) & 1;
                const int mm = ((u >> 3) << 2) | (u & 3);
                uint2 w2;
                w2.x = permpack(v[1], v[0]);
                w2.y = permpack(v[3], v[2]);
                *(uint2*)&k2[((((((size_t)(b * HH + h)) * 24 + c32) * 2 + half) * 4 + quad) * 16 + mm) * 4] = w2;
            } else {
                const int h = ((n0 - 256) >> 4) + nt;
                const size_t vb = (((size_t)(b * HH + h)) * 24 + c32) * 512;
                #pragma unroll
                for (int r = 0; r < 4; ++r)
                    v2[vb + (quad * 4 + r) * 32 + u] = f2b(v[r]);
            }
        }
    }
}

// ---------------------------------------------------------------------------
// MFMA flash attention v9 (unchanged).
// ---------------------------------------------------------------------------
__device__ __forceinline__ void attn_step32(
    bf16x4 kf0, bf16x4 kf1, bf16x8 vf, const bf16x4 (&qf)[2],
    f32x4 (&oacc)[2], f32x4 (&lacc)[2], bf16x8 ones8)
{
    const f32x4 zero4 = (f32x4){0.f, 0.f, 0.f, 0.f};
    #pragma unroll
    for (int s = 0; s < 2; ++s) {
        f32x4 sv0 = __builtin_amdgcn_mfma_f32_16x16x16bf16_1k(kf0, qf[s], zero4, 0, 0, 0);
        f32x4 sv1 = __builtin_amdgcn_mfma_f32_16x16x16bf16_1k(kf1, qf[s], zero4, 0, 0, 0);
        float e0 = __builtin_amdgcn_exp2f(sv0[0]);
        float e1 = __builtin_amdgcn_exp2f(sv0[1]);
        float e2 = __builtin_amdgcn_exp2f(sv0[2]);
        float e3 = __builtin_amdgcn_exp2f(sv0[3]);
        float e4 = __builtin_amdgcn_exp2f(sv1[0]);
        float e5 = __builtin_amdgcn_exp2f(sv1[1]);
        float e6 = __builtin_amdgcn_exp2f(sv1[2]);
        float e7 = __builtin_amdgcn_exp2f(sv1[3]);
        u32x4 pu;
        pu[0] = permpack(e1, e0);
        pu[1] = permpack(e3, e2);
        pu[2] = permpack(e5, e4);
        pu[3] = permpack(e7, e6);
        bf16x8 pf = __builtin_bit_cast(bf16x8, pu);
        oacc[s] = __builtin_amdgcn_mfma_f32_16x16x32_bf16(vf, pf, oacc[s], 0, 0, 0);
        lacc[s] = __builtin_amdgcn_mfma_f32_16x16x32_bf16(ones8, pf, lacc[s], 0, 0, 0);
    }
}

__global__ __launch_bounds__(256) void attention_mfma(
    const ushort_t* __restrict__ q_bf, const ushort_t* __restrict__ k2,
    const ushort_t* __restrict__ v2, ushort_t* __restrict__ ctx)
{
    const int bh = blockIdx.x;
    const int b = bh & 31, h = bh >> 5;     // XCD swizzle: id%8 == b%8
    const int qb = blockIdx.y;              // 0..5, 128 q each
    const int t = threadIdx.x;
    const int wave = t >> 6, lane = t & 63;
    const int quad = lane >> 4, l16 = lane & 15;
    const int hoff = h * 16;

    // Q fragments (one-time gather)
    bf16x4 qf[2];
    #pragma unroll
    for (int s = 0; s < 2; ++s) {
        int row = b * LSEQ + qb * 128 + wave * 32 + s * 16 + l16;
        qf[s] = *(const bf16x4*)&q_bf[(size_t)row * EE + hoff + quad * 4];
    }

    const int bhn = b * HH + h;
    const ushort_t* kp = k2 + (size_t)bhn * 12288 + quad * 64 + l16 * 4;
    const ushort_t* vp = v2 + (size_t)bhn * 12288 + l16 * 32 + quad * 8;

    f32x4 oacc[2], lacc[2];
    oacc[0] = (f32x4){0.f, 0.f, 0.f, 0.f};
    oacc[1] = (f32x4){0.f, 0.f, 0.f, 0.f};
    lacc[0] = (f32x4){0.f, 0.f, 0.f, 0.f};
    lacc[1] = (f32x4){0.f, 0.f, 0.f, 0.f};
    bf16x8 ones8;
    #pragma unroll
    for (int j = 0; j < 8; ++j) ones8[j] = (short)0x3F80;   // bf16 1.0

    bf16x4 k0a = *(const bf16x4*)(kp);
    bf16x4 k1a = *(const bf16x4*)(kp + 256);
    bf16x8 va  = *(const bf16x8*)(vp);
    bf16x4 k0b = *(const bf16x4*)(kp + 512);
    bf16x4 k1b = *(const bf16x4*)(kp + 768);
    bf16x8 vb  = *(const bf16x8*)(vp + 512);
    bf16x4 k0c = *(const bf16x4*)(kp + 1024);
    bf16x4 k1c = *(const bf16x4*)(kp + 1280);
    bf16x8 vc  = *(const bf16x8*)(vp + 1024);

    for (int c0 = 0; c0 < 24; c0 += 3) {
        attn_step32(k0a, k1a, va, qf, oacc, lacc, ones8);
        { int n = c0 + 3; if (n >= 24) n -= 24;
          k0a = *(const bf16x4*)(kp + n * 512);
          k1a = *(const bf16x4*)(kp + n * 512 + 256);
          va  = *(const bf16x8*)(vp + n * 512); }
        attn_step32(k0b, k1b, vb, qf, oacc, lacc, ones8);
        { int n = c0 + 4; if (n >= 24) n -= 24;
          k0b = *(const bf16x4*)(kp + n * 512);
          k1b = *(const bf16x4*)(kp + n * 512 + 256);
          vb  = *(const bf16x8*)(vp + n * 512); }
        attn_step32(k0c, k1c, vc, qf, oacc, lacc, ones8);
        { int n = c0 + 5; if (n >= 24) n -= 24;
          k0c = *(const bf16x4*)(kp + n * 512);
          k1c = *(const bf16x4*)(kp + n * 512 + 256);
          vc  = *(const bf16x8*)(vp + n * 512); }
    }

    #pragma unroll
    for (int s = 0; s < 2; ++s) {
        const float inv = 1.f / lacc[s][0];     // row-replicated full sum
        const int q = qb * 128 + wave * 32 + s * 16 + l16;
        uint2 w2;
        w2.x = permpack(oacc[s][1] * inv, oacc[s][0] * inv);
        w2.y = permpack(oacc[s][3] * inv, oacc[s][2] * inv);
        *(uint2*)&ctx[((size_t)(b * LSEQ + q)) * EE + hoff + quad * 4] = w2;
    }
}

// ---------------------------------------------------------------------------
// Fused attn-out GEMM + LN1 + FFN + LN2, v4: 96-row blocks x 384 threads
// (6 waves) -> grid = ROWS/96 = exactly 256 = 1 block/CU, perfect balance
// (R7's 384 blocks = 1.5/CU left half the CUs running 2 serial blocks).
// Per-wave structure identical (each wave owns 16 rows end-to-end); Wout
// staging amortized over 96 rows (was 64). LDS 75776 B.
// ---------------------------------------------------------------------------
#define W1OFF 0
#define W2OFF 8704
#define YOFF  17920
#define HOFF  30976
__global__ __launch_bounds__(384) void gemm_ln_ffn(
    const ushort_t* __restrict__ ctx_bf, const ushort_t* __restrict__ Wout,
    const float* __restrict__ bout,
    const float* __restrict__ g1, const float* __restrict__ be1,
    const ushort_t* __restrict__ W1, const float* __restrict__ b1,
    const ushort_t* __restrict__ W2, const float* __restrict__ b2,
    const float* __restrict__ g2, const float* __restrict__ be2,
    ushort_t* __restrict__ seq_bf)
{
    __shared__ ushort_t S[37888];           // 75776 B
    const int t = threadIdx.x;
    const int wave = t >> 6, lane = t & 63;
    const int quad = lane >> 4, l16 = lane & 15;
    const int m0 = blockIdx.x * 96;
    const int lrow = wave * 16 + l16;       // 0..95
    const int m = m0 + lrow;

    // ---- stage Wout (128 x 136) into S[0..17408 elems) ----
    for (int c = t; c < 128 * 16; c += 384) {
        int row = c >> 4, col = c & 15;
        *(bf16x8*)&S[row * 136 + col * 8] =
            *(const bf16x8*)&Wout[(size_t)row * 128 + col * 8];
    }
    __syncthreads();

    // ---- GEMM A: attn_out = ctx @ Wout^T ----
    f32x4 acc[8];
    #pragma unroll
    for (int nt = 0; nt < 8; ++nt) acc[nt] = (f32x4){0.f, 0.f, 0.f, 0.f};
    {
        const ushort_t* ap = ctx_bf + (size_t)m * EE + quad * 8;
        const ushort_t* wp = &S[l16 * 136 + quad * 8];
        #pragma unroll
        for (int k0 = 0; k0 < 128; k0 += 32) {
            bf16x8 a = *(const bf16x8*)(ap + k0);
            #pragma unroll
            for (int nt = 0; nt < 8; ++nt) {
                bf16x8 wf = *(const bf16x8*)(wp + nt * 16 * 136 + k0);
                acc[nt] = __builtin_amdgcn_mfma_f32_16x16x32_bf16(wf, a, acc[nt], 0, 0, 0);
            }
        }
    }
    __syncthreads();   // all waves done reading Wout; its LDS may be reused

    // ---- stage W1 (64x136) and W2 (128x72) over the Wout region ----
    for (int c = t; c < 64 * 16; c += 384) {
        int row = c >> 4, col = c & 15;
        *(bf16x8*)&S[W1OFF + row * 136 + col * 8] =
            *(const bf16x8*)&W1[(size_t)row * 128 + col * 8];
    }
    for (int c = t; c < 128 * 8; c += 384) {
        int row = c >> 3, col = c & 7;
        *(bf16x8*)&S[W2OFF + row * 72 + col * 8] =
            *(const bf16x8*)&W2[(size_t)row * 64 + col * 8];
    }

    // ---- epilogue A: + bias + residual(bf16), LN1 -> y (regs + LDS bf16) ----
    float y[8][4];
    float s = 0.f;
    #pragma unroll
    for (int nt = 0; nt < 8; ++nt) {
        const int nb = nt * 16 + quad * 4;
        float4 b4 = *(const float4*)&bout[nb];
        uint2 rr = *(const uint2*)&seq_bf[(size_t)m * EE + nb];
        float rv[4] = {blo(rr.x), bhi(rr.x), blo(rr.y), bhi(rr.y)};
        #pragma unroll
        for (int r = 0; r < 4; ++r) {
            y[nt][r] = acc[nt][r] + ((const float*)&b4)[r] + rv[r];
            s += y[nt][r];
        }
    }
    s += __shfl_xor(s, 16);
    s += __shfl_xor(s, 32);
    float mean = s * (1.f / 128.f);
    float s2 = 0.f;
    #pragma unroll
    for (int nt = 0; nt < 8; ++nt)
        #pragma unroll
        for (int r = 0; r < 4; ++r) {
            float d = y[nt][r] - mean;
            s2 += d * d;
        }
    s2 += __shfl_xor(s2, 16);
    s2 += __shfl_xor(s2, 32);
    float rstd = 1.f / sqrtf(s2 * (1.f / 128.f) + 1e-5f);

    #pragma unroll
    for (int nt = 0; nt < 8; ++nt) {
        const int nb = nt * 16 + quad * 4;
        float4 g4 = *(const float4*)&g1[nb];
        float4 be4 = *(const float4*)&be1[nb];
        #pragma unroll
        for (int r = 0; r < 4; ++r)
            y[nt][r] = (y[nt][r] - mean) * rstd * ((const float*)&g4)[r] + ((const float*)&be4)[r];
        uint2 w2;
        w2.x = permpack(y[nt][1], y[nt][0]);
        w2.y = permpack(y[nt][3], y[nt][2]);
        *(uint2*)&S[YOFF + lrow * 136 + nb] = w2;
    }
    __syncthreads();   // Ybf + W1 + W2 visible

    // ---- GEMM 1: h = elu(y @ W1^T + b1) ----
    f32x4 acc1[4];
    #pragma unroll
    for (int nt = 0; nt < 4; ++nt) acc1[nt] = (f32x4){0.f, 0.f, 0.f, 0.f};
    {
        const ushort_t* ap1 = &S[YOFF + lrow * 136 + quad * 8];
        const ushort_t* w1p = &S[W1OFF + l16 * 136 + quad * 8];
        #pragma unroll
        for (int k0 = 0; k0 < 128; k0 += 32) {
            bf16x8 a = *(const bf16x8*)(ap1 + k0);
            #pragma unroll
            for (int nt = 0; nt < 4; ++nt) {
                bf16x8 wf = *(const bf16x8*)(w1p + nt * 16 * 136 + k0);
                acc1[nt] = __builtin_amdgcn_mfma_f32_16x16x32_bf16(wf, a, acc1[nt], 0, 0, 0);
            }
        }
    }
    #pragma unroll
    for (int nt = 0; nt < 4; ++nt) {
        const int ib = nt * 16 + quad * 4;
        float4 b4 = *(const float4*)&b1[ib];
        float hv[4];
        #pragma unroll
        for (int r = 0; r < 4; ++r) {
            float u = acc1[nt][r] + ((const float*)&b4)[r];
            hv[r] = u > 0.f ? u : expm1f(u);
        }
        uint2 w2;
        w2.x = permpack(hv[1], hv[0]);
        w2.y = permpack(hv[3], hv[2]);
        *(uint2*)&S[HOFF + lrow * 72 + ib] = w2;   // wave-private rows
    }

    // ---- GEMM 2: ffn = h @ W2^T + b2 (reads only this lane's row) ----
    f32x4 acc2[8];
    #pragma unroll
    for (int nt = 0; nt < 8; ++nt) acc2[nt] = (f32x4){0.f, 0.f, 0.f, 0.f};
    {
        const ushort_t* hp  = &S[HOFF + lrow * 72 + quad * 8];
        const ushort_t* w2p = &S[W2OFF + l16 * 72 + quad * 8];
        #pragma unroll
        for (int k0 = 0; k0 < 64; k0 += 32) {
            bf16x8 hf = *(const bf16x8*)(hp + k0);
            #pragma unroll
            for (int nt = 0; nt < 8; ++nt) {
                bf16x8 wf = *(const bf16x8*)(w2p + nt * 16 * 72 + k0);
                acc2[nt] = __builtin_amdgcn_mfma_f32_16x16x32_bf16(wf, hf, acc2[nt], 0, 0, 0);
            }
        }
    }

    // ---- epilogue B: + bias + residual(y regs), LN2, store bf16 ----
    float v[8][4];
    s = 0.f;
    #pragma unroll
    for (int nt = 0; nt < 8; ++nt) {
        const int nb = nt * 16 + quad * 4;
        float4 b4 = *(const float4*)&b2[nb];
        #pragma unroll
        for (int r = 0; r < 4; ++r) {
            v[nt][r] = acc2[nt][r] + ((const float*)&b4)[r] + y[nt][r];
            s += v[nt][r];
        }
    }
    s += __shfl_xor(s, 16);
    s += __shfl_xor(s, 32);
    mean = s * (1.f / 128.f);
    s2 = 0.f;
    #pragma unroll
    for (int nt = 0; nt < 8; ++nt)
        #pragma unroll
        for (int r = 0; r < 4; ++r) {
            float d = v[nt][r] - mean;
            s2 += d * d;
        }
    s2 += __shfl_xor(s2, 16);
    s2 += __shfl_xor(s2, 32);
    rstd = 1.f / sqrtf(s2 * (1.f / 128.f) + 1e-5f);

    #pragma unroll
    for (int nt = 0; nt < 8; ++nt) {
        const int nb = nt * 16 + quad * 4;
        float4 g4 = *(const float4*)&g2[nb];
        float4 be4 = *(const float4*)&be2[nb];
        float o[4];
        #pragma unroll
        for (int r = 0; r < 4; ++r)
            o[r] = (v[nt][r] - mean) * rstd * ((const float*)&g4)[r] + ((const float*)&be4)[r];
        uint2 w2;
        w2.x = permpack(o[1], o[0]);
        w2.y = permpack(o[3], o[2]);
        *(uint2*)&seq_bf[(size_t)m * EE + nb] = w2;
    }
}

// ---------------------------------------------------------------------------
// Final projection, split-K MFMA (R7 shape: PKC 384, 256 blocks).
// ---------------------------------------------------------------------------
#define PKC 384
#define PNBLK (KOUT / PKC)   // 256
__global__ __launch_bounds__(256) void out_gemm3(
    const ushort_t* __restrict__ seqbf, const float* __restrict__ out_w,
    float* __restrict__ part)
{
    const int t = threadIdx.x;
    const int wave = t >> 6, lane = t & 63;
    const int quad = lane >> 4, l16 = lane & 15;
    const size_t k0 = (size_t)blockIdx.x * PKC;
    const int n0 = wave * 32;

    f32x4 acc[2][2];
    #pragma unroll
    for (int mt = 0; mt < 2; ++mt)
        #pragma unroll
        for (int nt = 0; nt < 2; ++nt)
            acc[mt][nt] = (f32x4){0.f, 0.f, 0.f, 0.f};

    const ushort_t* a0p = seqbf + (size_t)l16 * KOUT + k0 + quad * 8;
    const ushort_t* a1p = a0p + (size_t)16 * KOUT;
    const float* w0p = out_w + (size_t)(n0 + l16) * KOUT + k0 + quad * 8;
    const float* w1p = w0p + (size_t)16 * KOUT;

    for (int ks = 0; ks < PKC; ks += 32) {
        bf16x8 a0 = *(const bf16x8*)(a0p + ks);
        bf16x8 a1 = *(const bf16x8*)(a1p + ks);
        float4 wa0 = *(const float4*)(w0p + ks);
        float4 wa1 = *(const float4*)(w0p + ks + 4);
        float4 wb0 = *(const float4*)(w1p + ks);
        float4 wb1 = *(const float4*)(w1p + ks + 4);
        u32x4 b0, b1;
        b0[0] = permpack(wa0.y, wa0.x); b0[1] = permpack(wa0.w, wa0.z);
        b0[2] = permpack(wa1.y, wa1.x); b0[3] = permpack(wa1.w, wa1.z);
        b1[0] = permpack(wb0.y, wb0.x); b1[1] = permpack(wb0.w, wb0.z);
        b1[2] = permpack(wb1.y, wb1.x); b1[3] = permpack(wb1.w, wb1.z);
        bf16x8 bf0 = __builtin_bit_cast(bf16x8, b0);
        bf16x8 bf1 = __builtin_bit_cast(bf16x8, b1);
        acc[0][0] = __builtin_amdgcn_mfma_f32_16x16x32_bf16(a0, bf0, acc[0][0], 0, 0, 0);
        acc[1][0] = __builtin_amdgcn_mfma_f32_16x16x32_bf16(a1, bf0, acc[1][0], 0, 0, 0);
        acc[0][1] = __builtin_amdgcn_mfma_f32_16x16x32_bf16(a0, bf1, acc[0][1], 0, 0, 0);
        acc[1][1] = __builtin_amdgcn_mfma_f32_16x16x32_bf16(a1, bf1, acc[1][1], 0, 0, 0);
    }

    float* pb = part + (size_t)blockIdx.x * (32 * 128);
    #pragma unroll
    for (int mt = 0; mt < 2; ++mt)
        #pragma unroll
        for (int nt = 0; nt < 2; ++nt)
            #pragma unroll
            for (int r = 0; r < 4; ++r)
                pb[(mt * 16 + quad * 4 + r) * 128 + n0 + nt * 16 + l16] = acc[mt][nt][r];
}

// ---------------------------------------------------------------------------
// Single fused reduction over 256 split-K partials (R7 version): 128 blocks,
// 8 sub-sums of 32 partials each, LDS combine.
// ---------------------------------------------------------------------------
__global__ __launch_bounds__(256) void out_reduce(
    const float* __restrict__ part, const float* __restrict__ out_b,
    float* __restrict__ out)
{
    __shared__ float red[8][32];
    const int g = threadIdx.x & 31, sub = threadIdx.x >> 5;
    const int i = blockIdx.x * 32 + g;
    const float* p = part + (size_t)sub * 32 * 4096 + i;
    float s0 = 0.f, s1 = 0.f, s2 = 0.f, s3 = 0.f;
    for (int blk = 0; blk < 32; blk += 4) {
        s0 += p[(size_t)blk * 4096];
        s1 += p[(size_t)(blk + 1) * 4096];
        s2 += p[(size_t)(blk + 2) * 4096];
        s3 += p[(size_t)(blk + 3) * 4096];
    }
    red[sub][g] = (s0 + s1) + (s2 + s3);
    __syncthreads();
    if (sub == 0) {
        float s = 0.f;
        #pragma unroll
        for (int j = 0; j < 8; ++j) s += red[j][g];
        out[i] = out_b[i & (OUTN - 1)] + s;
    }
}

// ---------------------------------------------------------------------------
extern "C" void kernel_launch(void* const* d_in, const int* in_sizes, int n_in,
                              void* d_out, int out_size, void* d_ws, size_t ws_size,
                              hipStream_t stream)
{
    const float* x          = (const float*)d_in[0];
    const float* prototypes = (const float*)d_in[1];
    const float* emb_w      = (const float*)d_in[2];
    const float* emb_b      = (const float*)d_in[3];
    const float* proj_w     = (const float*)d_in[4];
    const float* proj_b     = (const float*)d_in[5];
    const float* in_proj_w  = (const float*)d_in[6];
    const float* in_proj_b  = (const float*)d_in[7];
    const float* out_proj_w = (const float*)d_in[8];
    const float* out_proj_b = (const float*)d_in[9];
    const float* ln1_s      = (const float*)d_in[10];
    const float* ln1_b      = (const float*)d_in[11];
    const float* ffn_w1     = (const float*)d_in[12];
    const float* ffn_b1     = (const float*)d_in[13];
    const float* ffn_w2     = (const float*)d_in[14];
    const float* ffn_b2     = (const float*)d_in[15];
    const float* ln2_s      = (const float*)d_in[16];
    const float* ln2_b      = (const float*)d_in[17];
    const float* out_w      = (const float*)d_in[18];
    const float* out_b      = (const float*)d_in[19];
    float* out = (float*)d_out;
    char* base = (char*)d_ws;

    float*    part   = (float*)base;                        // 4 MB
    ushort_t* seq_bf = (ushort_t*)(base + 25165824);        //  6,291,456
    ushort_t* q_bf   = (ushort_t*)(base + 31457280);        //  6,291,456
    ushort_t* k2     = (ushort_t*)(base + 37748736);        //  6,291,456
    ushort_t* v2     = (ushort_t*)(base + 44040192);        //  6,291,456
    ushort_t* ctx_bf = (ushort_t*)(base + 50331648);        //  6,291,456
    ushort_t* w_bf   = (ushort_t*)(base + 56623104);        //    327,680
    (void)ws_size;

    ushort_t* w_in  = w_bf;            // [2][384][128]
    ushort_t* w_out = w_bf + 98304;    // [2][128][128]
    ushort_t* w_f1  = w_bf + 131072;   // [2][64][128]
    ushort_t* w_f2  = w_bf + 147456;   // [2][128][64]

    // merged cast (320 blocks) + embed (3072 blocks, 8 rows each)
    cast_embed_kernel<<<NCAST + ROWS / 8, 512, 0, stream>>>(
        in_proj_w, 98304, out_proj_w, 32768, ffn_w1, 16384, ffn_w2, 16384,
        w_in, w_out, w_f1, w_f2,
        x, prototypes, emb_w, emb_b, proj_w, proj_b, seq_bf);

    for (int l = 0; l < 2; ++l) {
        gemm_qkv<<<dim3(6, 192), 256, 0, stream>>>(
            seq_bf, w_in + (size_t)l * 49152, in_proj_b + l * 384,
            q_bf, k2, v2);
        attention_mfma<<<dim3(BB * HH, 6), 256, 0, stream>>>(q_bf, k2, v2, ctx_bf);
        // seq = LN2(LN1(seq + ctx@Wout^T + b) + FFN(...)) fully fused
        gemm_ln_ffn<<<ROWS / 96, 384, 0, stream>>>(
            ctx_bf, w_out + (size_t)l * 16384, out_proj_b + l * 128,
            ln1_s + l * EE, ln1_b + l * EE,
            w_f1 + (size_t)l * 8192, ffn_b1 + l * II,
            w_f2 + (size_t)l * 8192, ffn_b2 + l * EE,
            ln2_s + l * EE, ln2_b + l * EE,
            seq_bf);
    }

    out_gemm3<<<PNBLK, 256, 0, stream>>>(seq_bf, out_w, part);
    out_reduce<<<OUTN * BB / 32, 256, 0, stream>>>(part, out_b, out);
}

// Round 10
// 248.052 us; speedup vs baseline: 1.0754x; 1.0346x over previous
//
#include <hip/hip_runtime.h>
#include <hip/hip_bf16.h>
#include <math.h>

typedef unsigned short ushort_t;
typedef unsigned int uint_t;

// Problem constants
#define BB 32
#define PP 6
#define DD 96
#define EE 128
#define HH 8
#define II 64
#define KK 32
#define LSEQ 768            // N*D
#define ROWS (BB * LSEQ)    // 24576 token rows
#define OUTN 128
#define KOUT (LSEQ * EE)    // 98304

using bf16x8 = __attribute__((ext_vector_type(8))) short;
using bf16x4 = __attribute__((ext_vector_type(4))) short;
using f32x4  = __attribute__((ext_vector_type(4))) float;
using u32x4  = __attribute__((ext_vector_type(4))) uint_t;

__device__ __forceinline__ ushort_t f2b(float f) {
    __hip_bfloat16 h = __float2bfloat16(f);
    return *reinterpret_cast<ushort_t*>(&h);
}
// pack two fp32 -> (bf16(hi)<<16)|bf16(lo) by TRUNCATION: one v_perm_b32.
__device__ __forceinline__ uint_t permpack(float hi, float lo) {
    return __builtin_amdgcn_perm(__builtin_bit_cast(uint_t, hi),
                                 __builtin_bit_cast(uint_t, lo), 0x07060302u);
}
__device__ __forceinline__ float blo(uint_t u) {
    return __builtin_bit_cast(float, u << 16);
}
__device__ __forceinline__ float bhi(uint_t u) {
    return __builtin_bit_cast(float, u & 0xffff0000u);
}

// ---------------------------------------------------------------------------
// Merged cast + embed (unchanged from R9).
// ---------------------------------------------------------------------------
#define NCAST 320
__global__ __launch_bounds__(512) void cast_embed_kernel(
    const float* __restrict__ s0, int n0, const float* __restrict__ s1, int n1,
    const float* __restrict__ s2, int n2, const float* __restrict__ s3, int n3,
    ushort_t* __restrict__ d0, ushort_t* __restrict__ d1,
    ushort_t* __restrict__ d2, ushort_t* __restrict__ d3,
    const float* __restrict__ x, const float* __restrict__ prot,
    const float* __restrict__ emb_w, const float* __restrict__ emb_b,
    const float* __restrict__ proj_w, const float* __restrict__ proj_b,
    ushort_t* __restrict__ seq_bf)
{
    if (blockIdx.x < NCAST) {
        int i = blockIdx.x * 512 + threadIdx.x;
        if (i < n0) { d0[i] = f2b(s0[i]); return; }
        i -= n0;
        if (i < n1) { d1[i] = f2b(s1[i]); return; }
        i -= n1;
        if (i < n2) { d2[i] = f2b(s2[i]); return; }
        i -= n2;
        if (i < n3) { d3[i] = f2b(s3[i]); }
        return;
    }

    const int wave = threadIdx.x >> 6, lane = threadIdx.x & 63;
    const int r = (blockIdx.x - NCAST) * 8 + wave;
    const int d = r % DD;
    const int lpos = r % LSEQ;

    float xr[PP];
    float nx = 0.f;
    #pragma unroll
    for (int p = 0; p < PP; ++p) { xr[p] = x[r * PP + p]; nx += xr[p] * xr[p]; }
    const float xinv = 1.f / fmaxf(sqrtf(nx), 1e-12f);

    // proto sims, duplicated across the two 32-lane halves
    const int tk = lane & 31;
    const float* pr = prot + (d * KK + tk) * PP;
    float np2 = 0.f, dot = 0.f;
    #pragma unroll
    for (int p = 0; p < PP; ++p) {
        float pv = pr[p];
        np2 += pv * pv;
        dot += xr[p] * pv;
    }
    const float pinv = 1.f / fmaxf(sqrtf(np2), 1e-12f);
    float sim = dot * xinv * pinv;
    int k = tk;
    #pragma unroll
    for (int off = 16; off; off >>= 1) {
        float osim = __shfl_xor(sim, off);
        int   ok   = __shfl_xor(k, off);
        if (osim > sim || (osim == sim && ok < k)) { sim = osim; k = ok; }
    }
    // selected proto, normalized (recompute norm; all lanes agree on k)
    const float* sr = prot + (d * KK + k) * PP;
    float sp[PP], sn2 = 0.f;
    #pragma unroll
    for (int p = 0; p < PP; ++p) { sp[p] = sr[p]; sn2 += sp[p] * sp[p]; }
    const float spinv = 1.f / fmaxf(sqrtf(sn2), 1e-12f);

    #pragma unroll
    for (int c = 0; c < 2; ++c) {
        const int t = lane + c * 64;
        float acc = emb_b[t] + proj_b[t];
        #pragma unroll
        for (int p = 0; p < PP; ++p) {
            acc = fmaf(xr[p], emb_w[t * PP + p], acc);
            acc = fmaf(sp[p] * spinv, proj_w[t * PP + p], acc);
        }
        const float twoj = (float)((t >> 1) * 2);
        const float div = __expf(twoj * (-9.210340371976184f / 128.0f));
        const float ang = (float)lpos * div;
        const float pe = (t & 1) ? __cosf(ang) : __sinf(ang);
        seq_bf[(size_t)r * EE + t] = f2b(acc + pe);
    }
}

// ---------------------------------------------------------------------------
// QKV GEMM v3: paired n-blocks. Grid (3, 192); each block stages a 128-row
// W panel (x=0: Q rows 0-127, x=1: K rows 128-255, x=2: V rows 256-383) and
// reuses each A-row load for 8 MFMAs (was 4) -> A re-reads halved, block
// count halved, epilogue branch remains block-uniform per panel.
// ---------------------------------------------------------------------------
__global__ __launch_bounds__(256) void gemm_qkv(
    const ushort_t* __restrict__ A, const ushort_t* __restrict__ W,
    const float* __restrict__ bias,
    ushort_t* __restrict__ q_bf, ushort_t* __restrict__ k2,
    ushort_t* __restrict__ v2)
{
    __shared__ ushort_t Ws[128 * 136];   // 34816 B
    const int t = threadIdx.x;
    const int wave = t >> 6, lane = t & 63;
    const int quad = lane >> 4, l16 = lane & 15;
    const int m0 = blockIdx.y * 128, n0 = blockIdx.x * 128;

    for (int c = t; c < 128 * 16; c += 256) {
        int row = c >> 4, col = c & 15;
        *(bf16x8*)&Ws[row * 136 + col * 8] =
            *(const bf16x8*)&W[(size_t)(n0 + row) * 128 + col * 8];
    }
    __syncthreads();

    f32x4 acc[2][2][4];   // [panel][s][nt]
    #pragma unroll
    for (int p = 0; p < 2; ++p)
        #pragma unroll
        for (int s = 0; s < 2; ++s)
            #pragma unroll
            for (int nt = 0; nt < 4; ++nt)
                acc[p][s][nt] = (f32x4){0.f, 0.f, 0.f, 0.f};

    const ushort_t* a0p = A + (size_t)(m0 + wave * 32 + l16) * 128 + quad * 8;
    const ushort_t* a1p = a0p + (size_t)16 * 128;
    const ushort_t* wp  = &Ws[l16 * 136 + quad * 8];

    #pragma unroll
    for (int k0 = 0; k0 < 128; k0 += 32) {
        bf16x8 a0 = *(const bf16x8*)(a0p + k0);
        bf16x8 a1 = *(const bf16x8*)(a1p + k0);
        #pragma unroll
        for (int p = 0; p < 2; ++p)
            #pragma unroll
            for (int nt = 0; nt < 4; ++nt) {
                bf16x8 wf = *(const bf16x8*)(wp + (p * 64 + nt * 16) * 136 + k0);
                acc[p][0][nt] = __builtin_amdgcn_mfma_f32_16x16x32_bf16(wf, a0, acc[p][0][nt], 0, 0, 0);
                acc[p][1][nt] = __builtin_amdgcn_mfma_f32_16x16x32_bf16(wf, a1, acc[p][1][nt], 0, 0, 0);
            }
    }

    const int b = blockIdx.y / 6;            // 6 m-blocks per batch (768/128)
    #pragma unroll
    for (int p = 0; p < 2; ++p) {
        const int n0p = n0 + p * 64;
        #pragma unroll
        for (int s = 0; s < 2; ++s) {
            const int m = m0 + wave * 32 + s * 16 + l16;
            const int l = m - b * LSEQ;          // position within sequence
            const int c32 = l >> 5, u = l & 31;
            #pragma unroll
            for (int nt = 0; nt < 4; ++nt) {
                const int nb = n0p + nt * 16 + quad * 4;
                float4 b4 = *(const float4*)&bias[nb];
                float v[4];
                #pragma unroll
                for (int r = 0; r < 4; ++r)
                    v[r] = acc[p][s][nt][r] + ((const float*)&b4)[r];

                if (n0p < 128) {
                    // Q: pre-scale by 1/sqrt(16) * log2(e)
                    #pragma unroll
                    for (int r = 0; r < 4; ++r) v[r] *= 0.36067376022224085f;
                    uint2 w2;
                    w2.x = permpack(v[1], v[0]);
                    w2.y = permpack(v[3], v[2]);
                    *(uint2*)&q_bf[(size_t)m * EE + nb] = w2;
                } else if (n0p < 256) {
                    const int h = ((n0p - 128) >> 4) + nt;
                    const int half = (u >> 2) & 1;
                    const int mm = ((u >> 3) << 2) | (u & 3);
                    uint2 w2;
                    w2.x = permpack(v[1], v[0]);
                    w2.y = permpack(v[3], v[2]);
                    *(uint2*)&k2[((((((size_t)(b * HH + h)) * 24 + c32) * 2 + half) * 4 + quad) * 16 + mm) * 4] = w2;
                } else {
                    const int h = ((n0p - 256) >> 4) + nt;
                    const size_t vb = (((size_t)(b * HH + h)) * 24 + c32) * 512;
                    #pragma unroll
                    for (int r = 0; r < 4; ++r)
                        v2[vb + (quad * 4 + r) * 32 + u] = f2b(v[r]);
                }
            }
        }
    }
}

// ---------------------------------------------------------------------------
// MFMA flash attention v9 (unchanged).
// ---------------------------------------------------------------------------
__device__ __forceinline__ void attn_step32(
    bf16x4 kf0, bf16x4 kf1, bf16x8 vf, const bf16x4 (&qf)[2],
    f32x4 (&oacc)[2], f32x4 (&lacc)[2], bf16x8 ones8)
{
    const f32x4 zero4 = (f32x4){0.f, 0.f, 0.f, 0.f};
    #pragma unroll
    for (int s = 0; s < 2; ++s) {
        f32x4 sv0 = __builtin_amdgcn_mfma_f32_16x16x16bf16_1k(kf0, qf[s], zero4, 0, 0, 0);
        f32x4 sv1 = __builtin_amdgcn_mfma_f32_16x16x16bf16_1k(kf1, qf[s], zero4, 0, 0, 0);
        float e0 = __builtin_amdgcn_exp2f(sv0[0]);
        float e1 = __builtin_amdgcn_exp2f(sv0[1]);
        float e2 = __builtin_amdgcn_exp2f(sv0[2]);
        float e3 = __builtin_amdgcn_exp2f(sv0[3]);
        float e4 = __builtin_amdgcn_exp2f(sv1[0]);
        float e5 = __builtin_amdgcn_exp2f(sv1[1]);
        float e6 = __builtin_amdgcn_exp2f(sv1[2]);
        float e7 = __builtin_amdgcn_exp2f(sv1[3]);
        u32x4 pu;
        pu[0] = permpack(e1, e0);
        pu[1] = permpack(e3, e2);
        pu[2] = permpack(e5, e4);
        pu[3] = permpack(e7, e6);
        bf16x8 pf = __builtin_bit_cast(bf16x8, pu);
        oacc[s] = __builtin_amdgcn_mfma_f32_16x16x32_bf16(vf, pf, oacc[s], 0, 0, 0);
        lacc[s] = __builtin_amdgcn_mfma_f32_16x16x32_bf16(ones8, pf, lacc[s], 0, 0, 0);
    }
}

__global__ __launch_bounds__(256) void attention_mfma(
    const ushort_t* __restrict__ q_bf, const ushort_t* __restrict__ k2,
    const ushort_t* __restrict__ v2, ushort_t* __restrict__ ctx)
{
    const int bh = blockIdx.x;
    const int b = bh & 31, h = bh >> 5;     // XCD swizzle: id%8 == b%8
    const int qb = blockIdx.y;              // 0..5, 128 q each
    const int t = threadIdx.x;
    const int wave = t >> 6, lane = t & 63;
    const int quad = lane >> 4, l16 = lane & 15;
    const int hoff = h * 16;

    // Q fragments (one-time gather)
    bf16x4 qf[2];
    #pragma unroll
    for (int s = 0; s < 2; ++s) {
        int row = b * LSEQ + qb * 128 + wave * 32 + s * 16 + l16;
        qf[s] = *(const bf16x4*)&q_bf[(size_t)row * EE + hoff + quad * 4];
    }

    const int bhn = b * HH + h;
    const ushort_t* kp = k2 + (size_t)bhn * 12288 + quad * 64 + l16 * 4;
    const ushort_t* vp = v2 + (size_t)bhn * 12288 + l16 * 32 + quad * 8;

    f32x4 oacc[2], lacc[2];
    oacc[0] = (f32x4){0.f, 0.f, 0.f, 0.f};
    oacc[1] = (f32x4){0.f, 0.f, 0.f, 0.f};
    lacc[0] = (f32x4){0.f, 0.f, 0.f, 0.f};
    lacc[1] = (f32x4){0.f, 0.f, 0.f, 0.f};
    bf16x8 ones8;
    #pragma unroll
    for (int j = 0; j < 8; ++j) ones8[j] = (short)0x3F80;   // bf16 1.0

    bf16x4 k0a = *(const bf16x4*)(kp);
    bf16x4 k1a = *(const bf16x4*)(kp + 256);
    bf16x8 va  = *(const bf16x8*)(vp);
    bf16x4 k0b = *(const bf16x4*)(kp + 512);
    bf16x4 k1b = *(const bf16x4*)(kp + 768);
    bf16x8 vb  = *(const bf16x8*)(vp + 512);
    bf16x4 k0c = *(const bf16x4*)(kp + 1024);
    bf16x4 k1c = *(const bf16x4*)(kp + 1280);
    bf16x8 vc  = *(const bf16x8*)(vp + 1024);

    for (int c0 = 0; c0 < 24; c0 += 3) {
        attn_step32(k0a, k1a, va, qf, oacc, lacc, ones8);
        { int n = c0 + 3; if (n >= 24) n -= 24;
          k0a = *(const bf16x4*)(kp + n * 512);
          k1a = *(const bf16x4*)(kp + n * 512 + 256);
          va  = *(const bf16x8*)(vp + n * 512); }
        attn_step32(k0b, k1b, vb, qf, oacc, lacc, ones8);
        { int n = c0 + 4; if (n >= 24) n -= 24;
          k0b = *(const bf16x4*)(kp + n * 512);
          k1b = *(const bf16x4*)(kp + n * 512 + 256);
          vb  = *(const bf16x8*)(vp + n * 512); }
        attn_step32(k0c, k1c, vc, qf, oacc, lacc, ones8);
        { int n = c0 + 5; if (n >= 24) n -= 24;
          k0c = *(const bf16x4*)(kp + n * 512);
          k1c = *(const bf16x4*)(kp + n * 512 + 256);
          vc  = *(const bf16x8*)(vp + n * 512); }
    }

    #pragma unroll
    for (int s = 0; s < 2; ++s) {
        const float inv = 1.f / lacc[s][0];     // row-replicated full sum
        const int q = qb * 128 + wave * 32 + s * 16 + l16;
        uint2 w2;
        w2.x = permpack(oacc[s][1] * inv, oacc[s][0] * inv);
        w2.y = permpack(oacc[s][3] * inv, oacc[s][2] * inv);
        *(uint2*)&ctx[((size_t)(b * LSEQ + q)) * EE + hoff + quad * 4] = w2;
    }
}

// ---------------------------------------------------------------------------
// Fused attn-out GEMM + LN1 + FFN + LN2 (unchanged from R9: 96-row blocks,
// 384 threads, grid 256 = 1 block/CU).
// ---------------------------------------------------------------------------
#define W1OFF 0
#define W2OFF 8704
#define YOFF  17920
#define HOFF  30976
__global__ __launch_bounds__(384) void gemm_ln_ffn(
    const ushort_t* __restrict__ ctx_bf, const ushort_t* __restrict__ Wout,
    const float* __restrict__ bout,
    const float* __restrict__ g1, const float* __restrict__ be1,
    const ushort_t* __restrict__ W1, const float* __restrict__ b1,
    const ushort_t* __restrict__ W2, const float* __restrict__ b2,
    const float* __restrict__ g2, const float* __restrict__ be2,
    ushort_t* __restrict__ seq_bf)
{
    __shared__ ushort_t S[37888];           // 75776 B
    const int t = threadIdx.x;
    const int wave = t >> 6, lane = t & 63;
    const int quad = lane >> 4, l16 = lane & 15;
    const int m0 = blockIdx.x * 96;
    const int lrow = wave * 16 + l16;       // 0..95
    const int m = m0 + lrow;

    // ---- stage Wout (128 x 136) into S[0..17408 elems) ----
    for (int c = t; c < 128 * 16; c += 384) {
        int row = c >> 4, col = c & 15;
        *(bf16x8*)&S[row * 136 + col * 8] =
            *(const bf16x8*)&Wout[(size_t)row * 128 + col * 8];
    }
    __syncthreads();

    // ---- GEMM A: attn_out = ctx @ Wout^T ----
    f32x4 acc[8];
    #pragma unroll
    for (int nt = 0; nt < 8; ++nt) acc[nt] = (f32x4){0.f, 0.f, 0.f, 0.f};
    {
        const ushort_t* ap = ctx_bf + (size_t)m * EE + quad * 8;
        const ushort_t* wp = &S[l16 * 136 + quad * 8];
        #pragma unroll
        for (int k0 = 0; k0 < 128; k0 += 32) {
            bf16x8 a = *(const bf16x8*)(ap + k0);
            #pragma unroll
            for (int nt = 0; nt < 8; ++nt) {
                bf16x8 wf = *(const bf16x8*)(wp + nt * 16 * 136 + k0);
                acc[nt] = __builtin_amdgcn_mfma_f32_16x16x32_bf16(wf, a, acc[nt], 0, 0, 0);
            }
        }
    }
    __syncthreads();   // all waves done reading Wout; its LDS may be reused

    // ---- stage W1 (64x136) and W2 (128x72) over the Wout region ----
    for (int c = t; c < 64 * 16; c += 384) {
        int row = c >> 4, col = c & 15;
        *(bf16x8*)&S[W1OFF + row * 136 + col * 8] =
            *(const bf16x8*)&W1[(size_t)row * 128 + col * 8];
    }
    for (int c = t; c < 128 * 8; c += 384) {
        int row = c >> 3, col = c & 7;
        *(bf16x8*)&S[W2OFF + row * 72 + col * 8] =
            *(const bf16x8*)&W2[(size_t)row * 64 + col * 8];
    }

    // ---- epilogue A: + bias + residual(bf16), LN1 -> y (regs + LDS bf16) ----
    float y[8][4];
    float s = 0.f;
    #pragma unroll
    for (int nt = 0; nt < 8; ++nt) {
        const int nb = nt * 16 + quad * 4;
        float4 b4 = *(const float4*)&bout[nb];
        uint2 rr = *(const uint2*)&seq_bf[(size_t)m * EE + nb];
        float rv[4] = {blo(rr.x), bhi(rr.x), blo(rr.y), bhi(rr.y)};
        #pragma unroll
        for (int r = 0; r < 4; ++r) {
            y[nt][r] = acc[nt][r] + ((const float*)&b4)[r] + rv[r];
            s += y[nt][r];
        }
    }
    s += __shfl_xor(s, 16);
    s += __shfl_xor(s, 32);
    float mean = s * (1.f / 128.f);
    float s2 = 0.f;
    #pragma unroll
    for (int nt = 0; nt < 8; ++nt)
        #pragma unroll
        for (int r = 0; r < 4; ++r) {
            float d = y[nt][r] - mean;
            s2 += d * d;
        }
    s2 += __shfl_xor(s2, 16);
    s2 += __shfl_xor(s2, 32);
    float rstd = 1.f / sqrtf(s2 * (1.f / 128.f) + 1e-5f);

    #pragma unroll
    for (int nt = 0; nt < 8; ++nt) {
        const int nb = nt * 16 + quad * 4;
        float4 g4 = *(const float4*)&g1[nb];
        float4 be4 = *(const float4*)&be1[nb];
        #pragma unroll
        for (int r = 0; r < 4; ++r)
            y[nt][r] = (y[nt][r] - mean) * rstd * ((const float*)&g4)[r] + ((const float*)&be4)[r];
        uint2 w2;
        w2.x = permpack(y[nt][1], y[nt][0]);
        w2.y = permpack(y[nt][3], y[nt][2]);
        *(uint2*)&S[YOFF + lrow * 136 + nb] = w2;
    }
    __syncthreads();   // Ybf + W1 + W2 visible

    // ---- GEMM 1: h = elu(y @ W1^T + b1) ----
    f32x4 acc1[4];
    #pragma unroll
    for (int nt = 0; nt < 4; ++nt) acc1[nt] = (f32x4){0.f, 0.f, 0.f, 0.f};
    {
        const ushort_t* ap1 = &S[YOFF + lrow * 136 + quad * 8];
        const ushort_t* w1p = &S[W1OFF + l16 * 136 + quad * 8];
        #pragma unroll
        for (int k0 = 0; k0 < 128; k0 += 32) {
            bf16x8 a = *(const bf16x8*)(ap1 + k0);
            #pragma unroll
            for (int nt = 0; nt < 4; ++nt) {
                bf16x8 wf = *(const bf16x8*)(w1p + nt * 16 * 136 + k0);
                acc1[nt] = __builtin_amdgcn_mfma_f32_16x16x32_bf16(wf, a, acc1[nt], 0, 0, 0);
            }
        }
    }
    #pragma unroll
    for (int nt = 0; nt < 4; ++nt) {
        const int ib = nt * 16 + quad * 4;
        float4 b4 = *(const float4*)&b1[ib];
        float hv[4];
        #pragma unroll
        for (int r = 0; r < 4; ++r) {
            float u = acc1[nt][r] + ((const float*)&b4)[r];
            hv[r] = u > 0.f ? u : expm1f(u);
        }
        uint2 w2;
        w2.x = permpack(hv[1], hv[0]);
        w2.y = permpack(hv[3], hv[2]);
        *(uint2*)&S[HOFF + lrow * 72 + ib] = w2;   // wave-private rows
    }

    // ---- GEMM 2: ffn = h @ W2^T + b2 (reads only this lane's row) ----
    f32x4 acc2[8];
    #pragma unroll
    for (int nt = 0; nt < 8; ++nt) acc2[nt] = (f32x4){0.f, 0.f, 0.f, 0.f};
    {
        const ushort_t* hp  = &S[HOFF + lrow * 72 + quad * 8];
        const ushort_t* w2p = &S[W2OFF + l16 * 72 + quad * 8];
        #pragma unroll
        for (int k0 = 0; k0 < 64; k0 += 32) {
            bf16x8 hf = *(const bf16x8*)(hp + k0);
            #pragma unroll
            for (int nt = 0; nt < 8; ++nt) {
                bf16x8 wf = *(const bf16x8*)(w2p + nt * 16 * 72 + k0);
                acc2[nt] = __builtin_amdgcn_mfma_f32_16x16x32_bf16(wf, hf, acc2[nt], 0, 0, 0);
            }
        }
    }

    // ---- epilogue B: + bias + residual(y regs), LN2, store bf16 ----
    float v[8][4];
    s = 0.f;
    #pragma unroll
    for (int nt = 0; nt < 8; ++nt) {
        const int nb = nt * 16 + quad * 4;
        float4 b4 = *(const float4*)&b2[nb];
        #pragma unroll
        for (int r = 0; r < 4; ++r) {
            v[nt][r] = acc2[nt][r] + ((const float*)&b4)[r] + y[nt][r];
            s += v[nt][r];
        }
    }
    s += __shfl_xor(s, 16);
    s += __shfl_xor(s, 32);
    mean = s * (1.f / 128.f);
    s2 = 0.f;
    #pragma unroll
    for (int nt = 0; nt < 8; ++nt)
        #pragma unroll
        for (int r = 0; r < 4; ++r) {
            float d = v[nt][r] - mean;
            s2 += d * d;
        }
    s2 += __shfl_xor(s2, 16);
    s2 += __shfl_xor(s2, 32);
    rstd = 1.f / sqrtf(s2 * (1.f / 128.f) + 1e-5f);

    #pragma unroll
    for (int nt = 0; nt < 8; ++nt) {
        const int nb = nt * 16 + quad * 4;
        float4 g4 = *(const float4*)&g2[nb];
        float4 be4 = *(const float4*)&be2[nb];
        float o[4];
        #pragma unroll
        for (int r = 0; r < 4; ++r)
            o[r] = (v[nt][r] - mean) * rstd * ((const float*)&g4)[r] + ((const float*)&be4)[r];
        uint2 w2;
        w2.x = permpack(o[1], o[0]);
        w2.y = permpack(o[3], o[2]);
        *(uint2*)&seq_bf[(size_t)m * EE + nb] = w2;
    }
}

// ---------------------------------------------------------------------------
// Final projection, split-K MFMA (unchanged: PKC 384, 256 blocks).
// ---------------------------------------------------------------------------
#define PKC 384
#define PNBLK (KOUT / PKC)   // 256
__global__ __launch_bounds__(256) void out_gemm3(
    const ushort_t* __restrict__ seqbf, const float* __restrict__ out_w,
    float* __restrict__ part)
{
    const int t = threadIdx.x;
    const int wave = t >> 6, lane = t & 63;
    const int quad = lane >> 4, l16 = lane & 15;
    const size_t k0 = (size_t)blockIdx.x * PKC;
    const int n0 = wave * 32;

    f32x4 acc[2][2];
    #pragma unroll
    for (int mt = 0; mt < 2; ++mt)
        #pragma unroll
        for (int nt = 0; nt < 2; ++nt)
            acc[mt][nt] = (f32x4){0.f, 0.f, 0.f, 0.f};

    const ushort_t* a0p = seqbf + (size_t)l16 * KOUT + k0 + quad * 8;
    const ushort_t* a1p = a0p + (size_t)16 * KOUT;
    const float* w0p = out_w + (size_t)(n0 + l16) * KOUT + k0 + quad * 8;
    const float* w1p = w0p + (size_t)16 * KOUT;

    for (int ks = 0; ks < PKC; ks += 32) {
        bf16x8 a0 = *(const bf16x8*)(a0p + ks);
        bf16x8 a1 = *(const bf16x8*)(a1p + ks);
        float4 wa0 = *(const float4*)(w0p + ks);
        float4 wa1 = *(const float4*)(w0p + ks + 4);
        float4 wb0 = *(const float4*)(w1p + ks);
        float4 wb1 = *(const float4*)(w1p + ks + 4);
        u32x4 b0, b1;
        b0[0] = permpack(wa0.y, wa0.x); b0[1] = permpack(wa0.w, wa0.z);
        b0[2] = permpack(wa1.y, wa1.x); b0[3] = permpack(wa1.w, wa1.z);
        b1[0] = permpack(wb0.y, wb0.x); b1[1] = permpack(wb0.w, wb0.z);
        b1[2] = permpack(wb1.y, wb1.x); b1[3] = permpack(wb1.w, wb1.z);
        bf16x8 bf0 = __builtin_bit_cast(bf16x8, b0);
        bf16x8 bf1 = __builtin_bit_cast(bf16x8, b1);
        acc[0][0] = __builtin_amdgcn_mfma_f32_16x16x32_bf16(a0, bf0, acc[0][0], 0, 0, 0);
        acc[1][0] = __builtin_amdgcn_mfma_f32_16x16x32_bf16(a1, bf0, acc[1][0], 0, 0, 0);
        acc[0][1] = __builtin_amdgcn_mfma_f32_16x16x32_bf16(a0, bf1, acc[0][1], 0, 0, 0);
        acc[1][1] = __builtin_amdgcn_mfma_f32_16x16x32_bf16(a1, bf1, acc[1][1], 0, 0, 0);
    }

    float* pb = part + (size_t)blockIdx.x * (32 * 128);
    #pragma unroll
    for (int mt = 0; mt < 2; ++mt)
        #pragma unroll
        for (int nt = 0; nt < 2; ++nt)
            #pragma unroll
            for (int r = 0; r < 4; ++r)
                pb[(mt * 16 + quad * 4 + r) * 128 + n0 + nt * 16 + l16] = acc[mt][nt][r];
}

// ---------------------------------------------------------------------------
// Single fused reduction over 256 split-K partials (unchanged).
// ---------------------------------------------------------------------------
__global__ __launch_bounds__(256) void out_reduce(
    const float* __restrict__ part, const float* __restrict__ out_b,
    float* __restrict__ out)
{
    __shared__ float red[8][32];
    const int g = threadIdx.x & 31, sub = threadIdx.x >> 5;
    const int i = blockIdx.x * 32 + g;
    const float* p = part + (size_t)sub * 32 * 4096 + i;
    float s0 = 0.f, s1 = 0.f, s2 = 0.f, s3 = 0.f;
    for (int blk = 0; blk < 32; blk += 4) {
        s0 += p[(size_t)blk * 4096];
        s1 += p[(size_t)(blk + 1) * 4096];
        s2 += p[(size_t)(blk + 2) * 4096];
        s3 += p[(size_t)(blk + 3) * 4096];
    }
    red[sub][g] = (s0 + s1) + (s2 + s3);
    __syncthreads();
    if (sub == 0) {
        float s = 0.f;
        #pragma unroll
        for (int j = 0; j < 8; ++j) s += red[j][g];
        out[i] = out_b[i & (OUTN - 1)] + s;
    }
}

// ---------------------------------------------------------------------------
extern "C" void kernel_launch(void* const* d_in, const int* in_sizes, int n_in,
                              void* d_out, int out_size, void* d_ws, size_t ws_size,
                              hipStream_t stream)
{
    const float* x          = (const float*)d_in[0];
    const float* prototypes = (const float*)d_in[1];
    const float* emb_w      = (const float*)d_in[2];
    const float* emb_b      = (const float*)d_in[3];
    const float* proj_w     = (const float*)d_in[4];
    const float* proj_b     = (const float*)d_in[5];
    const float* in_proj_w  = (const float*)d_in[6];
    const float* in_proj_b  = (const float*)d_in[7];
    const float* out_proj_w = (const float*)d_in[8];
    const float* out_proj_b = (const float*)d_in[9];
    const float* ln1_s      = (const float*)d_in[10];
    const float* ln1_b      = (const float*)d_in[11];
    const float* ffn_w1     = (const float*)d_in[12];
    const float* ffn_b1     = (const float*)d_in[13];
    const float* ffn_w2     = (const float*)d_in[14];
    const float* ffn_b2     = (const float*)d_in[15];
    const float* ln2_s      = (const float*)d_in[16];
    const float* ln2_b      = (const float*)d_in[17];
    const float* out_w      = (const float*)d_in[18];
    const float* out_b      = (const float*)d_in[19];
    float* out = (float*)d_out;
    char* base = (char*)d_ws;

    float*    part   = (float*)base;                        // 4 MB
    ushort_t* seq_bf = (ushort_t*)(base + 25165824);        //  6,291,456
    ushort_t* q_bf   = (ushort_t*)(base + 31457280);        //  6,291,456
    ushort_t* k2     = (ushort_t*)(base + 37748736);        //  6,291,456
    ushort_t* v2     = (ushort_t*)(base + 44040192);        //  6,291,456
    ushort_t* ctx_bf = (ushort_t*)(base + 50331648);        //  6,291,456
    ushort_t* w_bf   = (ushort_t*)(base + 56623104);        //    327,680
    (void)ws_size;

    ushort_t* w_in  = w_bf;            // [2][384][128]
    ushort_t* w_out = w_bf + 98304;    // [2][128][128]
    ushort_t* w_f1  = w_bf + 131072;   // [2][64][128]
    ushort_t* w_f2  = w_bf + 147456;   // [2][128][64]

    // merged cast (320 blocks) + embed (3072 blocks, 8 rows each)
    cast_embed_kernel<<<NCAST + ROWS / 8, 512, 0, stream>>>(
        in_proj_w, 98304, out_proj_w, 32768, ffn_w1, 16384, ffn_w2, 16384,
        w_in, w_out, w_f1, w_f2,
        x, prototypes, emb_w, emb_b, proj_w, proj_b, seq_bf);

    for (int l = 0; l < 2; ++l) {
        gemm_qkv<<<dim3(3, 192), 256, 0, stream>>>(
            seq_bf, w_in + (size_t)l * 49152, in_proj_b + l * 384,
            q_bf, k2, v2);
        attention_mfma<<<dim3(BB * HH, 6), 256, 0, stream>>>(q_bf, k2, v2, ctx_bf);
        // seq = LN2(LN1(seq + ctx@Wout^T + b) + FFN(...)) fully fused
        gemm_ln_ffn<<<ROWS / 96, 384, 0, stream>>>(
            ctx_bf, w_out + (size_t)l * 16384, out_proj_b + l * 128,
            ln1_s + l * EE, ln1_b + l * EE,
            w_f1 + (size_t)l * 8192, ffn_b1 + l * II,
            w_f2 + (size_t)l * 8192, ffn_b2 + l * EE,
            ln2_s + l * EE, ln2_b + l * EE,
            seq_bf);
    }

    out_gemm3<<<PNBLK, 256, 0, stream>>>(seq_bf, out_w, part);
    out_reduce<<<OUTN * BB / 32, 256, 0, stream>>>(part, out_b, out);
}

// Round 11
// 246.241 us; speedup vs baseline: 1.0833x; 1.0074x over previous
//
#include <hip/hip_runtime.h>
#include <hip/hip_bf16.h>
#include <math.h>

typedef unsigned short ushort_t;
typedef unsigned int uint_t;

// Problem constants
#define BB 32
#define PP 6
#define DD 96
#define EE 128
#define HH 8
#define II 64
#define KK 32
#define LSEQ 768            // N*D
#define ROWS (BB * LSEQ)    // 24576 token rows
#define OUTN 128
#define KOUT (LSEQ * EE)    // 98304

using bf16x8 = __attribute__((ext_vector_type(8))) short;
using bf16x4 = __attribute__((ext_vector_type(4))) short;
using f32x4  = __attribute__((ext_vector_type(4))) float;
using u32x4  = __attribute__((ext_vector_type(4))) uint_t;

__device__ __forceinline__ ushort_t f2b(float f) {
    __hip_bfloat16 h = __float2bfloat16(f);
    return *reinterpret_cast<ushort_t*>(&h);
}
// pack two fp32 -> (bf16(hi)<<16)|bf16(lo) by TRUNCATION: one v_perm_b32.
__device__ __forceinline__ uint_t permpack(float hi, float lo) {
    return __builtin_amdgcn_perm(__builtin_bit_cast(uint_t, hi),
                                 __builtin_bit_cast(uint_t, lo), 0x07060302u);
}
__device__ __forceinline__ float blo(uint_t u) {
    return __builtin_bit_cast(float, u << 16);
}
__device__ __forceinline__ float bhi(uint_t u) {
    return __builtin_bit_cast(float, u & 0xffff0000u);
}

// ---------------------------------------------------------------------------
// Merged cast + embed (unchanged from R10).
// ---------------------------------------------------------------------------
#define NCAST 320
__global__ __launch_bounds__(512) void cast_embed_kernel(
    const float* __restrict__ s0, int n0, const float* __restrict__ s1, int n1,
    const float* __restrict__ s2, int n2, const float* __restrict__ s3, int n3,
    ushort_t* __restrict__ d0, ushort_t* __restrict__ d1,
    ushort_t* __restrict__ d2, ushort_t* __restrict__ d3,
    const float* __restrict__ x, const float* __restrict__ prot,
    const float* __restrict__ emb_w, const float* __restrict__ emb_b,
    const float* __restrict__ proj_w, const float* __restrict__ proj_b,
    ushort_t* __restrict__ seq_bf)
{
    if (blockIdx.x < NCAST) {
        int i = blockIdx.x * 512 + threadIdx.x;
        if (i < n0) { d0[i] = f2b(s0[i]); return; }
        i -= n0;
        if (i < n1) { d1[i] = f2b(s1[i]); return; }
        i -= n1;
        if (i < n2) { d2[i] = f2b(s2[i]); return; }
        i -= n2;
        if (i < n3) { d3[i] = f2b(s3[i]); }
        return;
    }

    const int wave = threadIdx.x >> 6, lane = threadIdx.x & 63;
    const int r = (blockIdx.x - NCAST) * 8 + wave;
    const int d = r % DD;
    const int lpos = r % LSEQ;

    float xr[PP];
    float nx = 0.f;
    #pragma unroll
    for (int p = 0; p < PP; ++p) { xr[p] = x[r * PP + p]; nx += xr[p] * xr[p]; }
    const float xinv = 1.f / fmaxf(sqrtf(nx), 1e-12f);

    // proto sims, duplicated across the two 32-lane halves
    const int tk = lane & 31;
    const float* pr = prot + (d * KK + tk) * PP;
    float np2 = 0.f, dot = 0.f;
    #pragma unroll
    for (int p = 0; p < PP; ++p) {
        float pv = pr[p];
        np2 += pv * pv;
        dot += xr[p] * pv;
    }
    const float pinv = 1.f / fmaxf(sqrtf(np2), 1e-12f);
    float sim = dot * xinv * pinv;
    int k = tk;
    #pragma unroll
    for (int off = 16; off; off >>= 1) {
        float osim = __shfl_xor(sim, off);
        int   ok   = __shfl_xor(k, off);
        if (osim > sim || (osim == sim && ok < k)) { sim = osim; k = ok; }
    }
    // selected proto, normalized (recompute norm; all lanes agree on k)
    const float* sr = prot + (d * KK + k) * PP;
    float sp[PP], sn2 = 0.f;
    #pragma unroll
    for (int p = 0; p < PP; ++p) { sp[p] = sr[p]; sn2 += sp[p] * sp[p]; }
    const float spinv = 1.f / fmaxf(sqrtf(sn2), 1e-12f);

    #pragma unroll
    for (int c = 0; c < 2; ++c) {
        const int t = lane + c * 64;
        float acc = emb_b[t] + proj_b[t];
        #pragma unroll
        for (int p = 0; p < PP; ++p) {
            acc = fmaf(xr[p], emb_w[t * PP + p], acc);
            acc = fmaf(sp[p] * spinv, proj_w[t * PP + p], acc);
        }
        const float twoj = (float)((t >> 1) * 2);
        const float div = __expf(twoj * (-9.210340371976184f / 128.0f));
        const float ang = (float)lpos * div;
        const float pe = (t & 1) ? __cosf(ang) : __sinf(ang);
        seq_bf[(size_t)r * EE + t] = f2b(acc + pe);
    }
}

// ---------------------------------------------------------------------------
// QKV GEMM v3: paired n-blocks (unchanged from R10; it won -8.6 us).
// ---------------------------------------------------------------------------
__global__ __launch_bounds__(256) void gemm_qkv(
    const ushort_t* __restrict__ A, const ushort_t* __restrict__ W,
    const float* __restrict__ bias,
    ushort_t* __restrict__ q_bf, ushort_t* __restrict__ k2,
    ushort_t* __restrict__ v2)
{
    __shared__ ushort_t Ws[128 * 136];   // 34816 B
    const int t = threadIdx.x;
    const int wave = t >> 6, lane = t & 63;
    const int quad = lane >> 4, l16 = lane & 15;
    const int m0 = blockIdx.y * 128, n0 = blockIdx.x * 128;

    for (int c = t; c < 128 * 16; c += 256) {
        int row = c >> 4, col = c & 15;
        *(bf16x8*)&Ws[row * 136 + col * 8] =
            *(const bf16x8*)&W[(size_t)(n0 + row) * 128 + col * 8];
    }
    __syncthreads();

    f32x4 acc[2][2][4];   // [panel][s][nt]
    #pragma unroll
    for (int p = 0; p < 2; ++p)
        #pragma unroll
        for (int s = 0; s < 2; ++s)
            #pragma unroll
            for (int nt = 0; nt < 4; ++nt)
                acc[p][s][nt] = (f32x4){0.f, 0.f, 0.f, 0.f};

    const ushort_t* a0p = A + (size_t)(m0 + wave * 32 + l16) * 128 + quad * 8;
    const ushort_t* a1p = a0p + (size_t)16 * 128;
    const ushort_t* wp  = &Ws[l16 * 136 + quad * 8];

    #pragma unroll
    for (int k0 = 0; k0 < 128; k0 += 32) {
        bf16x8 a0 = *(const bf16x8*)(a0p + k0);
        bf16x8 a1 = *(const bf16x8*)(a1p + k0);
        #pragma unroll
        for (int p = 0; p < 2; ++p)
            #pragma unroll
            for (int nt = 0; nt < 4; ++nt) {
                bf16x8 wf = *(const bf16x8*)(wp + (p * 64 + nt * 16) * 136 + k0);
                acc[p][0][nt] = __builtin_amdgcn_mfma_f32_16x16x32_bf16(wf, a0, acc[p][0][nt], 0, 0, 0);
                acc[p][1][nt] = __builtin_amdgcn_mfma_f32_16x16x32_bf16(wf, a1, acc[p][1][nt], 0, 0, 0);
            }
    }

    const int b = blockIdx.y / 6;            // 6 m-blocks per batch (768/128)
    #pragma unroll
    for (int p = 0; p < 2; ++p) {
        const int n0p = n0 + p * 64;
        #pragma unroll
        for (int s = 0; s < 2; ++s) {
            const int m = m0 + wave * 32 + s * 16 + l16;
            const int l = m - b * LSEQ;          // position within sequence
            const int c32 = l >> 5, u = l & 31;
            #pragma unroll
            for (int nt = 0; nt < 4; ++nt) {
                const int nb = n0p + nt * 16 + quad * 4;
                float4 b4 = *(const float4*)&bias[nb];
                float v[4];
                #pragma unroll
                for (int r = 0; r < 4; ++r)
                    v[r] = acc[p][s][nt][r] + ((const float*)&b4)[r];

                if (n0p < 128) {
                    // Q: pre-scale by 1/sqrt(16) * log2(e)
                    #pragma unroll
                    for (int r = 0; r < 4; ++r) v[r] *= 0.36067376022224085f;
                    uint2 w2;
                    w2.x = permpack(v[1], v[0]);
                    w2.y = permpack(v[3], v[2]);
                    *(uint2*)&q_bf[(size_t)m * EE + nb] = w2;
                } else if (n0p < 256) {
                    const int h = ((n0p - 128) >> 4) + nt;
                    const int half = (u >> 2) & 1;
                    const int mm = ((u >> 3) << 2) | (u & 3);
                    uint2 w2;
                    w2.x = permpack(v[1], v[0]);
                    w2.y = permpack(v[3], v[2]);
                    *(uint2*)&k2[((((((size_t)(b * HH + h)) * 24 + c32) * 2 + half) * 4 + quad) * 16 + mm) * 4] = w2;
                } else {
                    const int h = ((n0p - 256) >> 4) + nt;
                    const size_t vb = (((size_t)(b * HH + h)) * 24 + c32) * 512;
                    #pragma unroll
                    for (int r = 0; r < 4; ++r)
                        v2[vb + (quad * 4 + r) * 32 + u] = f2b(v[r]);
                }
            }
        }
    }
}

// ---------------------------------------------------------------------------
// MFMA flash attention v10: 64 q rows per wave (s=0..3). Each wave's K/V
// stream is amortized over 2x the q rows -> K/V VMEM issue count halves
// chip-wide, block count halves (grid (256,3) = 768 = exactly 3/CU), and
// load->use distance in the 3-deep pipeline doubles. Loads per chunk
// unchanged (3); MFMAs per chunk 8 -> 16.
// ---------------------------------------------------------------------------
__device__ __forceinline__ void attn_step32x4(
    bf16x4 kf0, bf16x4 kf1, bf16x8 vf, const bf16x4 (&qf)[4],
    f32x4 (&oacc)[4], f32x4 (&lacc)[4], bf16x8 ones8)
{
    const f32x4 zero4 = (f32x4){0.f, 0.f, 0.f, 0.f};
    #pragma unroll
    for (int s = 0; s < 4; ++s) {
        f32x4 sv0 = __builtin_amdgcn_mfma_f32_16x16x16bf16_1k(kf0, qf[s], zero4, 0, 0, 0);
        f32x4 sv1 = __builtin_amdgcn_mfma_f32_16x16x16bf16_1k(kf1, qf[s], zero4, 0, 0, 0);
        float e0 = __builtin_amdgcn_exp2f(sv0[0]);
        float e1 = __builtin_amdgcn_exp2f(sv0[1]);
        float e2 = __builtin_amdgcn_exp2f(sv0[2]);
        float e3 = __builtin_amdgcn_exp2f(sv0[3]);
        float e4 = __builtin_amdgcn_exp2f(sv1[0]);
        float e5 = __builtin_amdgcn_exp2f(sv1[1]);
        float e6 = __builtin_amdgcn_exp2f(sv1[2]);
        float e7 = __builtin_amdgcn_exp2f(sv1[3]);
        u32x4 pu;
        pu[0] = permpack(e1, e0);
        pu[1] = permpack(e3, e2);
        pu[2] = permpack(e5, e4);
        pu[3] = permpack(e7, e6);
        bf16x8 pf = __builtin_bit_cast(bf16x8, pu);
        oacc[s] = __builtin_amdgcn_mfma_f32_16x16x32_bf16(vf, pf, oacc[s], 0, 0, 0);
        lacc[s] = __builtin_amdgcn_mfma_f32_16x16x32_bf16(ones8, pf, lacc[s], 0, 0, 0);
    }
}

__global__ __launch_bounds__(256) void attention_mfma(
    const ushort_t* __restrict__ q_bf, const ushort_t* __restrict__ k2,
    const ushort_t* __restrict__ v2, ushort_t* __restrict__ ctx)
{
    const int bh = blockIdx.x;
    const int b = bh & 31, h = bh >> 5;     // XCD swizzle: id%8 == b%8
    const int qb = blockIdx.y;              // 0..2, 256 q each
    const int t = threadIdx.x;
    const int wave = t >> 6, lane = t & 63;
    const int quad = lane >> 4, l16 = lane & 15;
    const int hoff = h * 16;

    // Q fragments (one-time gather)
    bf16x4 qf[4];
    #pragma unroll
    for (int s = 0; s < 4; ++s) {
        int row = b * LSEQ + qb * 256 + wave * 64 + s * 16 + l16;
        qf[s] = *(const bf16x4*)&q_bf[(size_t)row * EE + hoff + quad * 4];
    }

    const int bhn = b * HH + h;
    const ushort_t* kp = k2 + (size_t)bhn * 12288 + quad * 64 + l16 * 4;
    const ushort_t* vp = v2 + (size_t)bhn * 12288 + l16 * 32 + quad * 8;

    f32x4 oacc[4], lacc[4];
    #pragma unroll
    for (int s = 0; s < 4; ++s) {
        oacc[s] = (f32x4){0.f, 0.f, 0.f, 0.f};
        lacc[s] = (f32x4){0.f, 0.f, 0.f, 0.f};
    }
    bf16x8 ones8;
    #pragma unroll
    for (int j = 0; j < 8; ++j) ones8[j] = (short)0x3F80;   // bf16 1.0

    bf16x4 k0a = *(const bf16x4*)(kp);
    bf16x4 k1a = *(const bf16x4*)(kp + 256);
    bf16x8 va  = *(const bf16x8*)(vp);
    bf16x4 k0b = *(const bf16x4*)(kp + 512);
    bf16x4 k1b = *(const bf16x4*)(kp + 768);
    bf16x8 vb  = *(const bf16x8*)(vp + 512);
    bf16x4 k0c = *(const bf16x4*)(kp + 1024);
    bf16x4 k1c = *(const bf16x4*)(kp + 1280);
    bf16x8 vc  = *(const bf16x8*)(vp + 1024);

    for (int c0 = 0; c0 < 24; c0 += 3) {
        attn_step32x4(k0a, k1a, va, qf, oacc, lacc, ones8);
        { int n = c0 + 3; if (n >= 24) n -= 24;
          k0a = *(const bf16x4*)(kp + n * 512);
          k1a = *(const bf16x4*)(kp + n * 512 + 256);
          va  = *(const bf16x8*)(vp + n * 512); }
        attn_step32x4(k0b, k1b, vb, qf, oacc, lacc, ones8);
        { int n = c0 + 4; if (n >= 24) n -= 24;
          k0b = *(const bf16x4*)(kp + n * 512);
          k1b = *(const bf16x4*)(kp + n * 512 + 256);
          vb  = *(const bf16x8*)(vp + n * 512); }
        attn_step32x4(k0c, k1c, vc, qf, oacc, lacc, ones8);
        { int n = c0 + 5; if (n >= 24) n -= 24;
          k0c = *(const bf16x4*)(kp + n * 512);
          k1c = *(const bf16x4*)(kp + n * 512 + 256);
          vc  = *(const bf16x8*)(vp + n * 512); }
    }

    #pragma unroll
    for (int s = 0; s < 4; ++s) {
        const float inv = 1.f / lacc[s][0];     // row-replicated full sum
        const int q = qb * 256 + wave * 64 + s * 16 + l16;
        uint2 w2;
        w2.x = permpack(oacc[s][1] * inv, oacc[s][0] * inv);
        w2.y = permpack(oacc[s][3] * inv, oacc[s][2] * inv);
        *(uint2*)&ctx[((size_t)(b * LSEQ + q)) * EE + hoff + quad * 4] = w2;
    }
}

// ---------------------------------------------------------------------------
// Fused attn-out GEMM + LN1 + FFN + LN2 (unchanged from R10: 96-row blocks,
// 384 threads, grid 256 = 1 block/CU).
// ---------------------------------------------------------------------------
#define W1OFF 0
#define W2OFF 8704
#define YOFF  17920
#define HOFF  30976
__global__ __launch_bounds__(384) void gemm_ln_ffn(
    const ushort_t* __restrict__ ctx_bf, const ushort_t* __restrict__ Wout,
    const float* __restrict__ bout,
    const float* __restrict__ g1, const float* __restrict__ be1,
    const ushort_t* __restrict__ W1, const float* __restrict__ b1,
    const ushort_t* __restrict__ W2, const float* __restrict__ b2,
    const float* __restrict__ g2, const float* __restrict__ be2,
    ushort_t* __restrict__ seq_bf)
{
    __shared__ ushort_t S[37888];           // 75776 B
    const int t = threadIdx.x;
    const int wave = t >> 6, lane = t & 63;
    const int quad = lane >> 4, l16 = lane & 15;
    const int m0 = blockIdx.x * 96;
    const int lrow = wave * 16 + l16;       // 0..95
    const int m = m0 + lrow;

    // ---- stage Wout (128 x 136) into S[0..17408 elems) ----
    for (int c = t; c < 128 * 16; c += 384) {
        int row = c >> 4, col = c & 15;
        *(bf16x8*)&S[row * 136 + col * 8] =
            *(const bf16x8*)&Wout[(size_t)row * 128 + col * 8];
    }
    __syncthreads();

    // ---- GEMM A: attn_out = ctx @ Wout^T ----
    f32x4 acc[8];
    #pragma unroll
    for (int nt = 0; nt < 8; ++nt) acc[nt] = (f32x4){0.f, 0.f, 0.f, 0.f};
    {
        const ushort_t* ap = ctx_bf + (size_t)m * EE + quad * 8;
        const ushort_t* wp = &S[l16 * 136 + quad * 8];
        #pragma unroll
        for (int k0 = 0; k0 < 128; k0 += 32) {
            bf16x8 a = *(const bf16x8*)(ap + k0);
            #pragma unroll
            for (int nt = 0; nt < 8; ++nt) {
                bf16x8 wf = *(const bf16x8*)(wp + nt * 16 * 136 + k0);
                acc[nt] = __builtin_amdgcn_mfma_f32_16x16x32_bf16(wf, a, acc[nt], 0, 0, 0);
            }
        }
    }
    __syncthreads();   // all waves done reading Wout; its LDS may be reused

    // ---- stage W1 (64x136) and W2 (128x72) over the Wout region ----
    for (int c = t; c < 64 * 16; c += 384) {
        int row = c >> 4, col = c & 15;
        *(bf16x8*)&S[W1OFF + row * 136 + col * 8] =
            *(const bf16x8*)&W1[(size_t)row * 128 + col * 8];
    }
    for (int c = t; c < 128 * 8; c += 384) {
        int row = c >> 3, col = c & 7;
        *(bf16x8*)&S[W2OFF + row * 72 + col * 8] =
            *(const bf16x8*)&W2[(size_t)row * 64 + col * 8];
    }

    // ---- epilogue A: + bias + residual(bf16), LN1 -> y (regs + LDS bf16) ----
    float y[8][4];
    float s = 0.f;
    #pragma unroll
    for (int nt = 0; nt < 8; ++nt) {
        const int nb = nt * 16 + quad * 4;
        float4 b4 = *(const float4*)&bout[nb];
        uint2 rr = *(const uint2*)&seq_bf[(size_t)m * EE + nb];
        float rv[4] = {blo(rr.x), bhi(rr.x), blo(rr.y), bhi(rr.y)};
        #pragma unroll
        for (int r = 0; r < 4; ++r) {
            y[nt][r] = acc[nt][r] + ((const float*)&b4)[r] + rv[r];
            s += y[nt][r];
        }
    }
    s += __shfl_xor(s, 16);
    s += __shfl_xor(s, 32);
    float mean = s * (1.f / 128.f);
    float s2 = 0.f;
    #pragma unroll
    for (int nt = 0; nt < 8; ++nt)
        #pragma unroll
        for (int r = 0; r < 4; ++r) {
            float d = y[nt][r] - mean;
            s2 += d * d;
        }
    s2 += __shfl_xor(s2, 16);
    s2 += __shfl_xor(s2, 32);
    float rstd = 1.f / sqrtf(s2 * (1.f / 128.f) + 1e-5f);

    #pragma unroll
    for (int nt = 0; nt < 8; ++nt) {
        const int nb = nt * 16 + quad * 4;
        float4 g4 = *(const float4*)&g1[nb];
        float4 be4 = *(const float4*)&be1[nb];
        #pragma unroll
        for (int r = 0; r < 4; ++r)
            y[nt][r] = (y[nt][r] - mean) * rstd * ((const float*)&g4)[r] + ((const float*)&be4)[r];
        uint2 w2;
        w2.x = permpack(y[nt][1], y[nt][0]);
        w2.y = permpack(y[nt][3], y[nt][2]);
        *(uint2*)&S[YOFF + lrow * 136 + nb] = w2;
    }
    __syncthreads();   // Ybf + W1 + W2 visible

    // ---- GEMM 1: h = elu(y @ W1^T + b1) ----
    f32x4 acc1[4];
    #pragma unroll
    for (int nt = 0; nt < 4; ++nt) acc1[nt] = (f32x4){0.f, 0.f, 0.f, 0.f};
    {
        const ushort_t* ap1 = &S[YOFF + lrow * 136 + quad * 8];
        const ushort_t* w1p = &S[W1OFF + l16 * 136 + quad * 8];
        #pragma unroll
        for (int k0 = 0; k0 < 128; k0 += 32) {
            bf16x8 a = *(const bf16x8*)(ap1 + k0);
            #pragma unroll
            for (int nt = 0; nt < 4; ++nt) {
                bf16x8 wf = *(const bf16x8*)(w1p + nt * 16 * 136 + k0);
                acc1[nt] = __builtin_amdgcn_mfma_f32_16x16x32_bf16(wf, a, acc1[nt], 0, 0, 0);
            }
        }
    }
    #pragma unroll
    for (int nt = 0; nt < 4; ++nt) {
        const int ib = nt * 16 + quad * 4;
        float4 b4 = *(const float4*)&b1[ib];
        float hv[4];
        #pragma unroll
        for (int r = 0; r < 4; ++r) {
            float u = acc1[nt][r] + ((const float*)&b4)[r];
            hv[r] = u > 0.f ? u : expm1f(u);
        }
        uint2 w2;
        w2.x = permpack(hv[1], hv[0]);
        w2.y = permpack(hv[3], hv[2]);
        *(uint2*)&S[HOFF + lrow * 72 + ib] = w2;   // wave-private rows
    }

    // ---- GEMM 2: ffn = h @ W2^T + b2 (reads only this lane's row) ----
    f32x4 acc2[8];
    #pragma unroll
    for (int nt = 0; nt < 8; ++nt) acc2[nt] = (f32x4){0.f, 0.f, 0.f, 0.f};
    {
        const ushort_t* hp  = &S[HOFF + lrow * 72 + quad * 8];
        const ushort_t* w2p = &S[W2OFF + l16 * 72 + quad * 8];
        #pragma unroll
        for (int k0 = 0; k0 < 64; k0 += 32) {
            bf16x8 hf = *(const bf16x8*)(hp + k0);
            #pragma unroll
            for (int nt = 0; nt < 8; ++nt) {
                bf16x8 wf = *(const bf16x8*)(w2p + nt * 16 * 72 + k0);
                acc2[nt] = __builtin_amdgcn_mfma_f32_16x16x32_bf16(wf, hf, acc2[nt], 0, 0, 0);
            }
        }
    }

    // ---- epilogue B: + bias + residual(y regs), LN2, store bf16 ----
    float v[8][4];
    s = 0.f;
    #pragma unroll
    for (int nt = 0; nt < 8; ++nt) {
        const int nb = nt * 16 + quad * 4;
        float4 b4 = *(const float4*)&b2[nb];
        #pragma unroll
        for (int r = 0; r < 4; ++r) {
            v[nt][r] = acc2[nt][r] + ((const float*)&b4)[r] + y[nt][r];
            s += v[nt][r];
        }
    }
    s += __shfl_xor(s, 16);
    s += __shfl_xor(s, 32);
    mean = s * (1.f / 128.f);
    s2 = 0.f;
    #pragma unroll
    for (int nt = 0; nt < 8; ++nt)
        #pragma unroll
        for (int r = 0; r < 4; ++r) {
            float d = v[nt][r] - mean;
            s2 += d * d;
        }
    s2 += __shfl_xor(s2, 16);
    s2 += __shfl_xor(s2, 32);
    rstd = 1.f / sqrtf(s2 * (1.f / 128.f) + 1e-5f);

    #pragma unroll
    for (int nt = 0; nt < 8; ++nt) {
        const int nb = nt * 16 + quad * 4;
        float4 g4 = *(const float4*)&g2[nb];
        float4 be4 = *(const float4*)&be2[nb];
        float o[4];
        #pragma unroll
        for (int r = 0; r < 4; ++r)
            o[r] = (v[nt][r] - mean) * rstd * ((const float*)&g4)[r] + ((const float*)&be4)[r];
        uint2 w2;
        w2.x = permpack(o[1], o[0]);
        w2.y = permpack(o[3], o[2]);
        *(uint2*)&seq_bf[(size_t)m * EE + nb] = w2;
    }
}

// ---------------------------------------------------------------------------
// Final projection, split-K MFMA (unchanged: PKC 384, 256 blocks).
// ---------------------------------------------------------------------------
#define PKC 384
#define PNBLK (KOUT / PKC)   // 256
__global__ __launch_bounds__(256) void out_gemm3(
    const ushort_t* __restrict__ seqbf, const float* __restrict__ out_w,
    float* __restrict__ part)
{
    const int t = threadIdx.x;
    const int wave = t >> 6, lane = t & 63;
    const int quad = lane >> 4, l16 = lane & 15;
    const size_t k0 = (size_t)blockIdx.x * PKC;
    const int n0 = wave * 32;

    f32x4 acc[2][2];
    #pragma unroll
    for (int mt = 0; mt < 2; ++mt)
        #pragma unroll
        for (int nt = 0; nt < 2; ++nt)
            acc[mt][nt] = (f32x4){0.f, 0.f, 0.f, 0.f};

    const ushort_t* a0p = seqbf + (size_t)l16 * KOUT + k0 + quad * 8;
    const ushort_t* a1p = a0p + (size_t)16 * KOUT;
    const float* w0p = out_w + (size_t)(n0 + l16) * KOUT + k0 + quad * 8;
    const float* w1p = w0p + (size_t)16 * KOUT;

    for (int ks = 0; ks < PKC; ks += 32) {
        bf16x8 a0 = *(const bf16x8*)(a0p + ks);
        bf16x8 a1 = *(const bf16x8*)(a1p + ks);
        float4 wa0 = *(const float4*)(w0p + ks);
        float4 wa1 = *(const float4*)(w0p + ks + 4);
        float4 wb0 = *(const float4*)(w1p + ks);
        float4 wb1 = *(const float4*)(w1p + ks + 4);
        u32x4 b0, b1;
        b0[0] = permpack(wa0.y, wa0.x); b0[1] = permpack(wa0.w, wa0.z);
        b0[2] = permpack(wa1.y, wa1.x); b0[3] = permpack(wa1.w, wa1.z);
        b1[0] = permpack(wb0.y, wb0.x); b1[1] = permpack(wb0.w, wb0.z);
        b1[2] = permpack(wb1.y, wb1.x); b1[3] = permpack(wb1.w, wb1.z);
        bf16x8 bf0 = __builtin_bit_cast(bf16x8, b0);
        bf16x8 bf1 = __builtin_bit_cast(bf16x8, b1);
        acc[0][0] = __builtin_amdgcn_mfma_f32_16x16x32_bf16(a0, bf0, acc[0][0], 0, 0, 0);
        acc[1][0] = __builtin_amdgcn_mfma_f32_16x16x32_bf16(a1, bf0, acc[1][0], 0, 0, 0);
        acc[0][1] = __builtin_amdgcn_mfma_f32_16x16x32_bf16(a0, bf1, acc[0][1], 0, 0, 0);
        acc[1][1] = __builtin_amdgcn_mfma_f32_16x16x32_bf16(a1, bf1, acc[1][1], 0, 0, 0);
    }

    float* pb = part + (size_t)blockIdx.x * (32 * 128);
    #pragma unroll
    for (int mt = 0; mt < 2; ++mt)
        #pragma unroll
        for (int nt = 0; nt < 2; ++nt)
            #pragma unroll
            for (int r = 0; r < 4; ++r)
                pb[(mt * 16 + quad * 4 + r) * 128 + n0 + nt * 16 + l16] = acc[mt][nt][r];
}

// ---------------------------------------------------------------------------
// Single fused reduction over 256 split-K partials (unchanged).
// ---------------------------------------------------------------------------
__global__ __launch_bounds__(256) void out_reduce(
    const float* __restrict__ part, const float* __restrict__ out_b,
    float* __restrict__ out)
{
    __shared__ float red[8][32];
    const int g = threadIdx.x & 31, sub = threadIdx.x >> 5;
    const int i = blockIdx.x * 32 + g;
    const float* p = part + (size_t)sub * 32 * 4096 + i;
    float s0 = 0.f, s1 = 0.f, s2 = 0.f, s3 = 0.f;
    for (int blk = 0; blk < 32; blk += 4) {
        s0 += p[(size_t)blk * 4096];
        s1 += p[(size_t)(blk + 1) * 4096];
        s2 += p[(size_t)(blk + 2) * 4096];
        s3 += p[(size_t)(blk + 3) * 4096];
    }
    red[sub][g] = (s0 + s1) + (s2 + s3);
    __syncthreads();
    if (sub == 0) {
        float s = 0.f;
        #pragma unroll
        for (int j = 0; j < 8; ++j) s += red[j][g];
        out[i] = out_b[i & (OUTN - 1)] + s;
    }
}

// ---------------------------------------------------------------------------
extern "C" void kernel_launch(void* const* d_in, const int* in_sizes, int n_in,
                              void* d_out, int out_size, void* d_ws, size_t ws_size,
                              hipStream_t stream)
{
    const float* x          = (const float*)d_in[0];
    const float* prototypes = (const float*)d_in[1];
    const float* emb_w      = (const float*)d_in[2];
    const float* emb_b      = (const float*)d_in[3];
    const float* proj_w     = (const float*)d_in[4];
    const float* proj_b     = (const float*)d_in[5];
    const float* in_proj_w  = (const float*)d_in[6];
    const float* in_proj_b  = (const float*)d_in[7];
    const float* out_proj_w = (const float*)d_in[8];
    const float* out_proj_b = (const float*)d_in[9];
    const float* ln1_s      = (const float*)d_in[10];
    const float* ln1_b      = (const float*)d_in[11];
    const float* ffn_w1     = (const float*)d_in[12];
    const float* ffn_b1     = (const float*)d_in[13];
    const float* ffn_w2     = (const float*)d_in[14];
    const float* ffn_b2     = (const float*)d_in[15];
    const float* ln2_s      = (const float*)d_in[16];
    const float* ln2_b      = (const float*)d_in[17];
    const float* out_w      = (const float*)d_in[18];
    const float* out_b      = (const float*)d_in[19];
    float* out = (float*)d_out;
    char* base = (char*)d_ws;

    float*    part   = (float*)base;                        // 4 MB
    ushort_t* seq_bf = (ushort_t*)(base + 25165824);        //  6,291,456
    ushort_t* q_bf   = (ushort_t*)(base + 31457280);        //  6,291,456
    ushort_t* k2     = (ushort_t*)(base + 37748736);        //  6,291,456
    ushort_t* v2     = (ushort_t*)(base + 44040192);        //  6,291,456
    ushort_t* ctx_bf = (ushort_t*)(base + 50331648);        //  6,291,456
    ushort_t* w_bf   = (ushort_t*)(base + 56623104);        //    327,680
    (void)ws_size;

    ushort_t* w_in  = w_bf;            // [2][384][128]
    ushort_t* w_out = w_bf + 98304;    // [2][128][128]
    ushort_t* w_f1  = w_bf + 131072;   // [2][64][128]
    ushort_t* w_f2  = w_bf + 147456;   // [2][128][64]

    // merged cast (320 blocks) + embed (3072 blocks, 8 rows each)
    cast_embed_kernel<<<NCAST + ROWS / 8, 512, 0, stream>>>(
        in_proj_w, 98304, out_proj_w, 32768, ffn_w1, 16384, ffn_w2, 16384,
        w_in, w_out, w_f1, w_f2,
        x, prototypes, emb_w, emb_b, proj_w, proj_b, seq_bf);

    for (int l = 0; l < 2; ++l) {
        gemm_qkv<<<dim3(3, 192), 256, 0, stream>>>(
            seq_bf, w_in + (size_t)l * 49152, in_proj_b + l * 384,
            q_bf, k2, v2);
        attention_mfma<<<dim3(BB * HH, 3), 256, 0, stream>>>(q_bf, k2, v2, ctx_bf);
        // seq = LN2(LN1(seq + ctx@Wout^T + b) + FFN(...)) fully fused
        gemm_ln_ffn<<<ROWS / 96, 384, 0, stream>>>(
            ctx_bf, w_out + (size_t)l * 16384, out_proj_b + l * 128,
            ln1_s + l * EE, ln1_b + l * EE,
            w_f1 + (size_t)l * 8192, ffn_b1 + l * II,
            w_f2 + (size_t)l * 8192, ffn_b2 + l * EE,
            ln2_s + l * EE, ln2_b + l * EE,
            seq_bf);
    }

    out_gemm3<<<PNBLK, 256, 0, stream>>>(seq_bf, out_w, part);
    out_reduce<<<OUTN * BB / 32, 256, 0, stream>>>(part, out_b, out);
}